// Round 5
// baseline (1184.752 us; speedup 1.0000x reference)
//
#include <hip/hip_runtime.h>

// ---------------------------------------------------------------------------
// AutoregressiveMatrixChain on MI355X, fp32.
// R5: Wfuse = W_pv@[W_op|T1|W_gate|W_stop_top] precomputed (kills per-iter
// stctx GEMM); setup GEMMs rewritten k-major/float4/conflict-free; qs1 psum
// combine folded into flash; cb+slotattn merged; ms folded into GRU A-stage.
// Per-iter chain: qs1, flash, cst, fw, combw, cbslot, k7, k8p, gru, k9b.
// ---------------------------------------------------------------------------

#define DINL __device__ __forceinline__

struct SG {
  const float* Bm;   // weight [K][N]
  const float* Bg;   // extra single column for n >= Ncore
  const float* a0;   // A source
  float* out;        // psums [KSg][M][ldo]
  int M, N, Ncore, NB, kslice, ksh, lda, ldb, ldo, mr;
  float scale;
};

DINL float dot4(float4 a, float4 b) {
  return fmaf(a.x, b.x, fmaf(a.y, b.y, fmaf(a.z, b.z, a.w * b.w)));
}
DINL unsigned sortable(float f) {
  unsigned u = __float_as_uint(f);
  return (u & 0x80000000u) ? ~u : (u | 0x80000000u);
}
#define AXPY4(A, W, P) \
  { A.x = fmaf(W, P.x, A.x); A.y = fmaf(W, P.y, A.y); A.z = fmaf(W, P.z, A.z); A.w = fmaf(W, P.w, A.w); }
#define ADD4(A, V) { A.x += V.x; A.y += V.y; A.z += V.z; A.w += V.w; }

// ---------------------------------------------------------------------------
// small GEMM: out[ks][m][n] = A[m,kslice]*B[kslice,n]*scale  (A raw)
// ---------------------------------------------------------------------------
template <int MR>
DINL void sgemm_body(const SG p, int bx, float* As) {
  const int t = threadIdx.x;
  const int ks = bx / p.NB, nb = bx % p.NB;
  const int kslice = p.kslice;
  const int kb = ks * kslice;

  const int tot = p.M * kslice;
  for (int idx = t; idx < tot; idx += 256) {
    const int m = idx >> p.ksh;
    const int kl = idx & (kslice - 1);
    As[(m << p.ksh) + kl] = p.a0[m * p.lda + kb + kl];
  }
  __syncthreads();

  const int nl = t & 63, mg = t >> 6;
  const int n = nb * 64 + nl;
  const bool nok = (n < p.N);
  float acc[MR];
#pragma unroll
  for (int i = 0; i < MR; i++) acc[i] = 0.f;

  const bool useg = nok && (n >= p.Ncore);
  const float* Bc = p.Bm + n;
  for (int k4 = 0; k4 < kslice; k4 += 4) {
    float bv[4];
#pragma unroll
    for (int u = 0; u < 4; u++) {
      bv[u] = 0.f;
      if (nok) bv[u] = useg ? p.Bg[kb + k4 + u] : Bc[(kb + k4 + u) * p.ldb];
    }
#pragma unroll
    for (int i = 0; i < MR; i++) {
      const int m = mg + 4 * i;
      if (MR == 4 || m < p.M) {
        const float4 av = *(const float4*)&As[(m << p.ksh) + k4];
        acc[i] = fmaf(av.x, bv[0], acc[i]);
        acc[i] = fmaf(av.y, bv[1], acc[i]);
        acc[i] = fmaf(av.z, bv[2], acc[i]);
        acc[i] = fmaf(av.w, bv[3], acc[i]);
      }
    }
  }

  if (nok) {
#pragma unroll
    for (int i = 0; i < MR; i++) {
      const int m = mg + 4 * i;
      if (MR == 4 || m < p.M) p.out[(ks * p.M + m) * p.ldo + n] = acc[i] * p.scale;
    }
  }
}

__global__ __launch_bounds__(256) void k_sgemm(SG p) {
  __shared__ __align__(16) float As[4352];
  if (p.mr == 4) sgemm_body<4>(p, blockIdx.x, As);
  else sgemm_body<7>(p, blockIdx.x, As);
}

// ---------------------------------------------------------------------------
// setup GEMM T: C = A@B^T*scale for (A1,B,C1) and (A2,B,C2). 1024^2 each.
// k-major LDS (pad 68): b128 reads, 2-way conflicts only. grid 512.
// ---------------------------------------------------------------------------
__global__ __launch_bounds__(256) void k_wgemmT(const float* __restrict__ A1,
                                                const float* __restrict__ B,
                                                float* __restrict__ C1,
                                                const float* __restrict__ A2,
                                                float* __restrict__ C2,
                                                float scale) {
  __shared__ __align__(16) float As[16 * 68], Bs[16 * 68];
  const int which = blockIdx.x >> 8;
  const int bid = blockIdx.x & 255;
  const float* A = which ? A2 : A1;
  float* C = which ? C2 : C1;
  const int bi = bid >> 4, bj = bid & 15;
  const int t = threadIdx.x;
  const int srow = t >> 2, sq = (t & 3) << 2;       // staging: row, k-quad
  const int r0 = (t >> 4) << 2, c0 = (t & 15) << 2; // compute subtile
  float acc[4][4];
#pragma unroll
  for (int i = 0; i < 4; i++)
#pragma unroll
    for (int j = 0; j < 4; j++) acc[i][j] = 0.f;

  const float* Arow = A + (bi * 64 + srow) * 1024 + sq;
  const float* Brow = B + (bj * 64 + srow) * 1024 + sq;
  for (int k0 = 0; k0 < 1024; k0 += 16) {
    const float4 av = *(const float4*)(Arow + k0);
    const float4 bv = *(const float4*)(Brow + k0);
    __syncthreads();
    As[(sq + 0) * 68 + srow] = av.x; As[(sq + 1) * 68 + srow] = av.y;
    As[(sq + 2) * 68 + srow] = av.z; As[(sq + 3) * 68 + srow] = av.w;
    Bs[(sq + 0) * 68 + srow] = bv.x; Bs[(sq + 1) * 68 + srow] = bv.y;
    Bs[(sq + 2) * 68 + srow] = bv.z; Bs[(sq + 3) * 68 + srow] = bv.w;
    __syncthreads();
#pragma unroll
    for (int kk = 0; kk < 16; kk++) {
      const float4 a4 = *(const float4*)&As[kk * 68 + r0];
      const float4 b4 = *(const float4*)&Bs[kk * 68 + c0];
      acc[0][0] = fmaf(a4.x, b4.x, acc[0][0]); acc[0][1] = fmaf(a4.x, b4.y, acc[0][1]);
      acc[0][2] = fmaf(a4.x, b4.z, acc[0][2]); acc[0][3] = fmaf(a4.x, b4.w, acc[0][3]);
      acc[1][0] = fmaf(a4.y, b4.x, acc[1][0]); acc[1][1] = fmaf(a4.y, b4.y, acc[1][1]);
      acc[1][2] = fmaf(a4.y, b4.z, acc[1][2]); acc[1][3] = fmaf(a4.y, b4.w, acc[1][3]);
      acc[2][0] = fmaf(a4.z, b4.x, acc[2][0]); acc[2][1] = fmaf(a4.z, b4.y, acc[2][1]);
      acc[2][2] = fmaf(a4.z, b4.z, acc[2][2]); acc[2][3] = fmaf(a4.z, b4.w, acc[2][3]);
      acc[3][0] = fmaf(a4.w, b4.x, acc[3][0]); acc[3][1] = fmaf(a4.w, b4.y, acc[3][1]);
      acc[3][2] = fmaf(a4.w, b4.z, acc[3][2]); acc[3][3] = fmaf(a4.w, b4.w, acc[3][3]);
    }
  }
#pragma unroll
  for (int i = 0; i < 4; i++) {
    const float4 v = make_float4(acc[i][0] * scale, acc[i][1] * scale,
                                 acc[i][2] * scale, acc[i][3] * scale);
    *(float4*)&C[(bi * 64 + r0 + i) * 1024 + bj * 64 + c0] = v;
  }
}

// ---------------------------------------------------------------------------
// setup GEMM F: Wfuse[1024][2056] = Wpv @ [Wop | T1 | Wgate | Wstop_top].
// A transposed-staged, B normal-staged. grid 16*33 = 528.
// ---------------------------------------------------------------------------
__global__ __launch_bounds__(256) void k_wgemmF(const float* __restrict__ Wpv,
                                                const float* __restrict__ Wop,
                                                const float* __restrict__ T1,
                                                const float* __restrict__ Wgate,
                                                const float* __restrict__ Wstop,
                                                float* __restrict__ Cf) {
  __shared__ __align__(16) float As[16 * 68], Bs[16 * 68];
  const int bi = blockIdx.x / 33, bj = blockIdx.x % 33;
  const int t = threadIdx.x;
  const int srow = t >> 2, sq = (t & 3) << 2;
  const int skk = t >> 4, snq = (t & 15) << 2;
  const int r0 = (t >> 4) << 2, c0 = (t & 15) << 2;
  float acc[4][4];
#pragma unroll
  for (int i = 0; i < 4; i++)
#pragma unroll
    for (int j = 0; j < 4; j++) acc[i][j] = 0.f;

  const float* Arow = Wpv + (bi * 64 + srow) * 1024 + sq;
  for (int k0 = 0; k0 < 1024; k0 += 16) {
    const float4 av = *(const float4*)(Arow + k0);
    float4 bv;
    if (bj < 16) {
      bv = *(const float4*)&Wop[(k0 + skk) * 1024 + bj * 64 + snq];
    } else if (bj < 32) {
      bv = *(const float4*)&T1[(k0 + skk) * 1024 + (bj - 16) * 64 + snq];
    } else {
      float b0 = 0.f, b1 = 0.f;
      if (snq == 0) { b0 = Wgate[k0 + skk]; b1 = Wstop[k0 + skk]; }
      bv = make_float4(b0, b1, 0.f, 0.f);
    }
    __syncthreads();
    As[(sq + 0) * 68 + srow] = av.x; As[(sq + 1) * 68 + srow] = av.y;
    As[(sq + 2) * 68 + srow] = av.z; As[(sq + 3) * 68 + srow] = av.w;
    *(float4*)&Bs[skk * 68 + snq] = bv;
    __syncthreads();
#pragma unroll
    for (int kk = 0; kk < 16; kk++) {
      const float4 a4 = *(const float4*)&As[kk * 68 + r0];
      const float4 b4 = *(const float4*)&Bs[kk * 68 + c0];
      acc[0][0] = fmaf(a4.x, b4.x, acc[0][0]); acc[0][1] = fmaf(a4.x, b4.y, acc[0][1]);
      acc[0][2] = fmaf(a4.x, b4.z, acc[0][2]); acc[0][3] = fmaf(a4.x, b4.w, acc[0][3]);
      acc[1][0] = fmaf(a4.y, b4.x, acc[1][0]); acc[1][1] = fmaf(a4.y, b4.y, acc[1][1]);
      acc[1][2] = fmaf(a4.y, b4.z, acc[1][2]); acc[1][3] = fmaf(a4.y, b4.w, acc[1][3]);
      acc[2][0] = fmaf(a4.z, b4.x, acc[2][0]); acc[2][1] = fmaf(a4.z, b4.y, acc[2][1]);
      acc[2][2] = fmaf(a4.z, b4.z, acc[2][2]); acc[2][3] = fmaf(a4.z, b4.w, acc[2][3]);
      acc[3][0] = fmaf(a4.w, b4.x, acc[3][0]); acc[3][1] = fmaf(a4.w, b4.y, acc[3][1]);
      acc[3][2] = fmaf(a4.w, b4.z, acc[3][2]); acc[3][3] = fmaf(a4.w, b4.w, acc[3][3]);
    }
  }
#pragma unroll
  for (int i = 0; i < 4; i++) {
    const int row = bi * 64 + r0 + i;
    if (bj < 32) {
      const float4 v = make_float4(acc[i][0], acc[i][1], acc[i][2], acc[i][3]);
      *(float4*)&Cf[row * 2056 + bj * 64 + c0] = v;
    } else if (c0 == 0) {
      Cf[row * 2056 + 2048] = acc[i][0];
      Cf[row * 2056 + 2049] = acc[i][1];
    }
  }
}

// ---------------------------------------------------------------------------
// per-iter wide GEMM: fwP = ctx @ Wfuse (N=2050). KSg=16, NB=33 -> 528 blocks.
// ---------------------------------------------------------------------------
__global__ __launch_bounds__(256) void k_fw(const float* __restrict__ ctx,
                                            const float* __restrict__ wfuse,
                                            float* __restrict__ outp) {
  __shared__ float As[1024];
  const int t = threadIdx.x;
  const int ks = blockIdx.x / 33, nb = blockIdx.x % 33;
  const int kb = ks * 64;
  for (int idx = t; idx < 1024; idx += 256) {
    As[idx] = ctx[((idx >> 6) << 10) + kb + (idx & 63)];
  }
  __syncthreads();
  const int nl = t & 63, mg = t >> 6;
  const int n = nb * 64 + nl;
  const bool nok = (n < 2050);
  const float* Bc = wfuse + n;
  float acc[4] = {0.f, 0.f, 0.f, 0.f};
  for (int k4 = 0; k4 < 64; k4 += 4) {
    float bv[4];
#pragma unroll
    for (int u = 0; u < 4; u++) bv[u] = nok ? Bc[(kb + k4 + u) * 2056] : 0.f;
#pragma unroll
    for (int i = 0; i < 4; i++) {
      const float4 av = *(const float4*)&As[((mg + 4 * i) << 6) + k4];
      acc[i] = fmaf(av.x, bv[0], acc[i]);
      acc[i] = fmaf(av.y, bv[1], acc[i]);
      acc[i] = fmaf(av.z, bv[2], acc[i]);
      acc[i] = fmaf(av.w, bv[3], acc[i]);
    }
  }
  if (nok) {
#pragma unroll
    for (int i = 0; i < 4; i++) outp[(ks * 16 + mg + 4 * i) * 2056 + n] = acc[i];
  }
}

// ---------------------------------------------------------------------------
// combine FW psums: opv (0..63), qsl (64..639), scalars (640)
// ---------------------------------------------------------------------------
__global__ __launch_bounds__(256) void k_combw(const float* __restrict__ fwP,
                                               const float* __restrict__ sqkcP,
                                               float* __restrict__ opv,
                                               float* __restrict__ qsl,
                                               float* __restrict__ gpre,
                                               float* __restrict__ gc,
                                               float* __restrict__ stopA) {
  const int bx = blockIdx.x;
  const int t = threadIdx.x;
  if (bx < 64) {
    const int i = bx * 256 + t;
    const int b = i >> 10, h = i & 1023;
    float s = 0.f;
    for (int p = 0; p < 16; p++) s += fwP[(p * 16 + b) * 2056 + h];
    opv[i] = s;
  } else if (bx < 640) {
    const int i = (bx - 64) * 256 + t;   // < 147456
    const int h = i & 1023;
    const int r = i >> 10;
    const int b = r / 9, j = r - b * 9;
    float s = 0.f;
    for (int p = 0; p < 16; p++) s += fwP[(p * 16 + b) * 2056 + 1024 + h];
    for (int sp = 0; sp < 4; sp++) s += sqkcP[(sp * 9 + j) * 1025 + h];
    qsl[i] = s;
  } else {
    if (t < 16) {
      float g = 0.f, sa = 0.f;
      for (int p = 0; p < 16; p++) {
        g += fwP[(p * 16 + t) * 2056 + 2048];
        sa += fwP[(p * 16 + t) * 2056 + 2049];
      }
      gpre[t] = g;
      stopA[t] = sa;
    } else if (t < 25) {
      const int j = t - 16;
      float g = 0.f;
      for (int sp = 0; sp < 4; sp++) g += sqkcP[(sp * 9 + j) * 1025 + 1024];
      gc[j] = g;
    }
  }
}

// ---------------------------------------------------------------------------
// merged: codebook argmax (blocks 0..255) + slot attention (blocks 256..767)
// ---------------------------------------------------------------------------
DINL void cb_body(int bx2, char* smem, const float* __restrict__ opv,
                  const float* __restrict__ cbv, const float* __restrict__ cbsqv,
                  unsigned long long* __restrict__ opmaxp) {
  const int t = threadIdx.x;
  for (int idx = t; idx < 16384; idx += 256) {
    const int x = idx << 2;
    *(float*)(smem + (x ^ (((x >> 7) & 7) << 4))) = opv[idx];
  }
  __syncthreads();
  const int w = t >> 6, l = t & 63;
  const int bxl = 64 * l;
  const int key = ((bxl >> 7) & 7) << 4;
  const int o0 = bxl ^ key, o1 = (bxl + 16) ^ key, o2 = (bxl + 32) ^ key, o3 = (bxl + 48) ^ key;
  unsigned long long bk[16];
#pragma unroll
  for (int m = 0; m < 16; m++) bk[m] = 0ull;
  const int cbase = (bx2 << 5) + (w << 3);
  for (int ci = 0; ci < 8; ci++) {
    const int c = cbase + ci;
    const float4* cr = (const float4*)(cbv + (c << 10));
    const float4 c0 = cr[4 * l], c1 = cr[4 * l + 1], c2 = cr[4 * l + 2], c3 = cr[4 * l + 3];
    float sm[16];
#pragma unroll
    for (int m = 0; m < 16; m++) {
      const char* qp = smem + (m << 12);
      const float4 a0 = *(const float4*)(qp + o0);
      const float4 a1 = *(const float4*)(qp + o1);
      const float4 a2 = *(const float4*)(qp + o2);
      const float4 a3 = *(const float4*)(qp + o3);
      sm[m] = dot4(a0, c0) + dot4(a1, c1) + dot4(a2, c2) + dot4(a3, c3);
    }
#pragma unroll
    for (int off = 32; off > 0; off >>= 1) {
#pragma unroll
      for (int m = 0; m < 16; m++) sm[m] += __shfl_xor(sm[m], off);
    }
    const float cq = cbsqv[c];
#pragma unroll
    for (int m = 0; m < 16; m++) {
      const float sc = fmaf(2.f, sm[m], -cq);
      const unsigned long long k2 = ((unsigned long long)sortable(sc) << 32) | (unsigned)(8192 - c);
      bk[m] = k2 > bk[m] ? k2 : bk[m];
    }
  }
  __syncthreads();
  unsigned long long* red = (unsigned long long*)smem;
  if (l == 0) {
#pragma unroll
    for (int m = 0; m < 16; m++) red[w * 16 + m] = bk[m];
  }
  __syncthreads();
  if (t < 16) {
    unsigned long long b2 = red[t];
    for (int ww = 1; ww < 4; ww++) {
      const unsigned long long v = red[ww * 16 + t];
      b2 = v > b2 ? v : b2;
    }
    opmaxp[bx2 * 16 + t] = b2;
  }
}

DINL void slot_body(int kc, int b, char* smem, const float* __restrict__ prompt,
                    const float* __restrict__ qsl, float* __restrict__ accp,
                    float* __restrict__ lpsum) {
  char* qsm = smem;                          // 36864 B
  float* wl = (float*)(smem + 36864);        // 576 floats
  float* lred = (float*)(smem + 36864 + 2304);
  const int t = threadIdx.x;
  for (int idx = t; idx < 9216; idx += 256) {
    const int x = idx << 2;
    *(float*)(qsm + (x ^ (((x >> 7) & 7) << 4))) = qsl[b * 9216 + idx];
  }
  __syncthreads();
  const int w = t >> 6, l = t & 63;
  const int bxl = 64 * l;
  const int key = ((bxl >> 7) & 7) << 4;
  const int o0 = bxl ^ key, o1 = (bxl + 16) ^ key, o2 = (bxl + 32) ^ key, o3 = (bxl + 48) ^ key;
  const int k0 = kc * 64 + w * 16;
  float lacc = 0.f;
  const float* pbase = prompt + ((b * 2048 + k0) << 10) + 16 * l;
  for (int ki = 0; ki < 16; ki++) {
    const float4* pr = (const float4*)(pbase + (ki << 10));
    const float4 p0 = pr[0], p1 = pr[1], p2 = pr[2], p3 = pr[3];
    float sj[9];
#pragma unroll
    for (int j = 0; j < 9; j++) {
      const char* qp = qsm + (j << 12);
      sj[j] = dot4(*(const float4*)(qp + o0), p0) + dot4(*(const float4*)(qp + o1), p1) +
              dot4(*(const float4*)(qp + o2), p2) + dot4(*(const float4*)(qp + o3), p3);
    }
#pragma unroll
    for (int off = 32; off > 0; off >>= 1) {
#pragma unroll
      for (int j = 0; j < 9; j++) sj[j] += __shfl_xor(sj[j], off);
    }
    float wv = sj[0];
#pragma unroll
    for (int j = 1; j < 9; j++)
      if (l == j) wv = sj[j];
    if (l < 9) {
      const float e = __expf(wv);
      wl[(w * 16 + ki) * 9 + l] = e;
      lacc += e;
    }
  }
  if (l < 9) lred[w * 9 + l] = lacc;
  __syncthreads();
  if (t < 9) lpsum[(b * 32 + kc) * 9 + t] = lred[t] + lred[9 + t] + lred[18 + t] + lred[27 + t];
  // phase 2: PV
  const int h4 = (w << 8) + (l << 2);
  float4 acc[9];
#pragma unroll
  for (int j = 0; j < 9; j++) acc[j] = make_float4(0.f, 0.f, 0.f, 0.f);
  const float* pb2 = prompt + ((b * 2048 + kc * 64) << 10) + h4;
#pragma unroll 2
  for (int k = 0; k < 64; k++) {
    const float4 pv = *(const float4*)(pb2 + (k << 10));
    const float* wr = &wl[k * 9];
#pragma unroll
    for (int j = 0; j < 9; j++) AXPY4(acc[j], wr[j], pv);
  }
  float* ob = accp + (((kc * 16 + b) * 9) << 10) + h4;
#pragma unroll
  for (int j = 0; j < 9; j++) *(float4*)(ob + (j << 10)) = acc[j];
}

__global__ __launch_bounds__(256) void k_cbslot(const float* __restrict__ opv,
                                                const float* __restrict__ cbv,
                                                const float* __restrict__ cbsqv,
                                                unsigned long long* __restrict__ opmaxp,
                                                const float* __restrict__ prompt,
                                                const float* __restrict__ qsl,
                                                float* __restrict__ accp,
                                                float* __restrict__ lpsum) {
  __shared__ __align__(16) char smem[65536];
  const int bx = blockIdx.x;
  if (bx < 256) {
    cb_body(bx, smem, opv, cbv, cbsqv, opmaxp);
  } else {
    const int idx = bx - 256;
    slot_body(idx & 31, idx >> 5, smem, prompt, qsl, accp, lpsum);
  }
}

// ---------------------------------------------------------------------------
// flash attention, state pass with inline 4-psum q combine. grid (32,16).
// ---------------------------------------------------------------------------
__global__ __launch_bounds__(256) void k_flash_state(const float* __restrict__ prompt,
                                                     const float* __restrict__ qs1P,
                                                     float* __restrict__ accst,
                                                     float* __restrict__ lst) {
  const int b = blockIdx.y;
  const int w = threadIdx.x >> 6, l = threadIdx.x & 63;
  const int chunk = blockIdx.x * 4 + w;  // 0..127
  float4 q0 = make_float4(0.f, 0.f, 0.f, 0.f), q1 = q0, q2 = q0, q3 = q0;
#pragma unroll
  for (int s = 0; s < 4; s++) {
    const float4* qp = (const float4*)(qs1P + ((s * 16 + b) << 10) + 16 * l);
    ADD4(q0, qp[0]); ADD4(q1, qp[1]); ADD4(q2, qp[2]); ADD4(q3, qp[3]);
  }
  float4 acc[4];
#pragma unroll
  for (int r = 0; r < 4; r++) acc[r] = make_float4(0.f, 0.f, 0.f, 0.f);
  float lsum = 0.f;
  const float* pbase = prompt + ((b * 2048 + chunk * 16) << 10) + 16 * l;
#pragma unroll 2
  for (int k = 0; k < 16; k++) {
    const float4* pr = (const float4*)(pbase + (k << 10));
    const float4 p0 = pr[0], p1 = pr[1], p2 = pr[2], p3 = pr[3];
    float s = dot4(q0, p0) + dot4(q1, p1) + dot4(q2, p2) + dot4(q3, p3);
#pragma unroll
    for (int off = 32; off > 0; off >>= 1) s += __shfl_xor(s, off);
    const float wgt = __expf(s);
    lsum += wgt;
    AXPY4(acc[0], wgt, p0); AXPY4(acc[1], wgt, p1);
    AXPY4(acc[2], wgt, p2); AXPY4(acc[3], wgt, p3);
  }
  float* ob = accst + ((chunk * 16 + b) << 10) + 16 * l;
#pragma unroll
  for (int r = 0; r < 4; r++) ((float4*)ob)[r] = acc[r];
  if (l == 0) lst[chunk * 16 + b] = lsum;
}

// combine state flash psums: ctx[b][h] = sum_c acc / sum_c l.  grid 256.
__global__ __launch_bounds__(256) void k_cst(const float* __restrict__ accst,
                                             const float* __restrict__ lst,
                                             float* __restrict__ ctx) {
  __shared__ float4 sred[256];
  __shared__ float rinv;
  const int bx = blockIdx.x;
  const int b = bx >> 4, hq = bx & 15;
  const int t = threadIdx.x;
  if (t < 64) {
    float s = 0.f;
    for (int c = t; c < 128; c += 64) s += lst[c * 16 + b];
#pragma unroll
    for (int off = 32; off > 0; off >>= 1) s += __shfl_xor(s, off);
    if (t == 0) rinv = 1.f / s;
  }
  const int h4 = hq * 16 + (t & 15);
  const int cp = t >> 4;
  float4 a = make_float4(0.f, 0.f, 0.f, 0.f);
#pragma unroll
  for (int ci = 0; ci < 8; ci++) {
    const int c = cp * 8 + ci;
    const float4 v = ((const float4*)accst)[((c * 16 + b) << 8) + h4];
    ADD4(a, v);
  }
  sred[t] = a;
  __syncthreads();
  if (t < 16) {
    float4 s = sred[t];
    for (int p2 = 1; p2 < 16; p2++) {
      const float4 v = sred[p2 * 16 + t];
      ADD4(s, v);
    }
    s.x *= rinv; s.y *= rinv; s.z *= rinv; s.w *= rinv;
    ((float4*)ctx)[(b << 8) + hq * 16 + t] = s;
  }
}

// ---------------------------------------------------------------------------
// K7: mask + masked mean (blocks 0..63); block 64: argmax finish -> opidx
// ---------------------------------------------------------------------------
__global__ __launch_bounds__(256) void k_k7(const float* __restrict__ accp,
                                            const float* __restrict__ lpsum,
                                            const float* __restrict__ gpre_g,
                                            const float* __restrict__ gc_g,
                                            const float* __restrict__ bgate,
                                            const unsigned long long* __restrict__ opmax,
                                            int* __restrict__ opidx,
                                            float* __restrict__ ssum) {
  __shared__ unsigned long long red[256];
  __shared__ float rl[9];
  __shared__ float gpre[16];
  __shared__ float gcs[9];
  __shared__ int mask_s[9];
  __shared__ float cntInv;
  const int bx = blockIdx.x;
  const int t = threadIdx.x;
  if (bx == 64) {
    const int b = t & 15, part = t >> 4;
    unsigned long long best = 0ull;
    for (int c = part * 16; c < part * 16 + 16; c++) {
      const unsigned long long v = opmax[c * 16 + b];
      best = v > best ? v : best;
    }
    red[t] = best;
    __syncthreads();
    if (t < 16) {
      unsigned long long m = red[t];
      for (int p2 = 1; p2 < 16; p2++) {
        const unsigned long long v = red[p2 * 16 + t];
        m = v > m ? v : m;
      }
      opidx[t] = 8192 - (int)(unsigned)(m & 0xFFFFFFFFull);
    }
    return;
  }
  const int b = bx >> 2;
  if (t < 9) {
    float s = 0.f;
    for (int c = 0; c < 32; c++) s += lpsum[(b * 32 + c) * 9 + t];
    rl[t] = 1.f / s;
  }
  if (t >= 32 && t < 48) gpre[t - 32] = gpre_g[t - 32];
  if (t >= 48 && t < 57) gcs[t - 48] = gc_g[t - 48];
  __syncthreads();
  if (t == 0) {
    const float bg = bgate[0];
    bool any = false;
    for (int bb = 0; bb < 16; bb++)
      for (int j = 0; j < 9; j++)
        if (gpre[bb] + gcs[j] + bg >= 0.f) any = true;
    int cnt = 0;
    if (any) {
      for (int j = 0; j < 9; j++) {
        const int s = (gpre[b] + gcs[j] + bg >= 0.f) ? 1 : 0;
        mask_s[j] = s;
        cnt += s;
      }
    } else {
      float bv = -3.4e38f;
      int bj = 0;
      for (int j = 0; j < 9; j++) {
        const float v = gpre[b] + gcs[j] + bg;
        if (v > bv) { bv = v; bj = j; }
      }
      for (int j = 0; j < 9; j++) mask_s[j] = (j == bj) ? 1 : 0;
      cnt = 1;
    }
    cntInv = 1.f / (float)(cnt > 0 ? cnt : 1);
  }
  __syncthreads();
  const int h = ((bx & 3) << 8) + t;
  float v = 0.f;
  for (int j = 0; j < 9; j++) {
    if (mask_s[j]) {
      float s = 0.f;
      for (int c = 0; c < 32; c++) s += accp[(((c * 16 + b) * 9 + j) << 10) + h];
      v = fmaf(s, rl[j], v);
    }
  }
  ssum[(b << 10) + h] = v * cntInv;
}

// ---------------------------------------------------------------------------
// GRU GEMM with fused ms=tanh(op_emb + k8p-sum) A-stage (blocks 0..383 = Wih
// side, writes ms + d_out from nb==0), blocks 384..767 = state@Whh side.
// ---------------------------------------------------------------------------
__global__ __launch_bounds__(256) void k_gru(const float* __restrict__ k8p,
                                             const int* __restrict__ opidx,
                                             const float* __restrict__ cbv,
                                             const float* __restrict__ state,
                                             const float* __restrict__ Wih,
                                             const float* __restrict__ Whh,
                                             float* __restrict__ gpP,
                                             float* __restrict__ ms,
                                             float* __restrict__ dout, int it) {
  __shared__ float As[2048];
  const int bx = blockIdx.x;
  const int t = threadIdx.x;
  const int half = (bx >= 384) ? 1 : 0;
  const int b2 = half ? bx - 384 : bx;
  const int ks = b2 / 48, nb = b2 % 48;
  const int kb = ks * 128;
  for (int idx = t; idx < 2048; idx += 256) {
    const int m = idx >> 7, kl = idx & 127;
    float v;
    if (!half) {
      float s = 0.f;
      for (int p = 0; p < 16; p++) s += k8p[((p * 16 + m) << 10) + kb + kl];
      v = tanhf(s + cbv[(opidx[m] << 10) + kb + kl]);
      if (nb == 0) {
        ms[(m << 10) + kb + kl] = v;
        dout[(m << 12) + (it << 10) + kb + kl] = v;
      }
    } else {
      v = state[(m << 10) + kb + kl];
    }
    As[idx] = v;
  }
  __syncthreads();
  const int nl = t & 63, mg = t >> 6;
  const int n = nb * 64 + nl;
  const float* Bc = (half ? Whh : Wih) + n;
  float acc[4] = {0.f, 0.f, 0.f, 0.f};
  for (int k4 = 0; k4 < 128; k4 += 4) {
    float bv[4];
#pragma unroll
    for (int u = 0; u < 4; u++) bv[u] = Bc[(kb + k4 + u) * 3072];
#pragma unroll
    for (int i = 0; i < 4; i++) {
      const float4 av = *(const float4*)&As[((mg + 4 * i) << 7) + k4];
      acc[i] = fmaf(av.x, bv[0], acc[i]);
      acc[i] = fmaf(av.y, bv[1], acc[i]);
      acc[i] = fmaf(av.z, bv[2], acc[i]);
      acc[i] = fmaf(av.w, bv[3], acc[i]);
    }
  }
  float* outp = gpP + half * 3072;
#pragma unroll
  for (int i = 0; i < 4; i++) outp[(ks * 16 + mg + 4 * i) * 6144 + n] = acc[i];
}

// ---------------------------------------------------------------------------
// K9b: GRU elementwise finish (0..63) + stop logits (64..67)
// ---------------------------------------------------------------------------
__global__ __launch_bounds__(256) void k_k9b(const float* __restrict__ gp,
                                             const float* __restrict__ bih,
                                             const float* __restrict__ bhh,
                                             float* __restrict__ state,
                                             const float* __restrict__ stopA,
                                             const float* __restrict__ ms,
                                             const float* __restrict__ Wstop,
                                             const float* __restrict__ bstop,
                                             float* __restrict__ dout, int it) {
  const int bx = blockIdx.x;
  const int t = threadIdx.x;
  if (bx < 64) {
    const int gi = bx * 256 + t;
    const int b = gi >> 10, h = gi & 1023;
    float ir = 0.f, iz = 0.f, inn = 0.f, hr = 0.f, hz = 0.f, hn = 0.f;
    for (int s = 0; s < 8; s++) {
      const float* g = gp + (s * 16 + b) * 6144;
      ir += g[h]; iz += g[1024 + h]; inn += g[2048 + h];
      hr += g[3072 + h]; hz += g[4096 + h]; hn += g[5120 + h];
    }
    ir += bih[h]; iz += bih[1024 + h]; inn += bih[2048 + h];
    hr += bhh[h]; hz += bhh[1024 + h]; hn += bhh[2048 + h];
    const float r = 1.f / (1.f + __expf(-(ir + hr)));
    const float z = 1.f / (1.f + __expf(-(iz + hz)));
    const float n = tanhf(fmaf(r, hn, inn));
    const float hold = state[gi];
    state[gi] = (1.f - z) * n + z * hold;
  } else {
    const int wid = (bx - 64) * 4 + (t >> 6);
    const int l = t & 63;
    float p = 0.f;
    for (int i = 0; i < 16; i++) {
      const int h = l + (i << 6);
      p = fmaf(ms[(wid << 10) + h], Wstop[1024 + h], p);
    }
#pragma unroll
    for (int off = 32; off > 0; off >>= 1) p += __shfl_xor(p, off);
    if (l == 0) {
      const float lg = p + stopA[wid] + bstop[0];
      dout[65536 + wid * 4 + it] = lg;
      dout[65600 + wid * 4 + it] = 1.f / (1.f + __expf(-lg));
    }
  }
}

__global__ void k_k10(float* __restrict__ dout) {
  const int t = threadIdx.x;
  if (t < 16) {
    int cl = 4;
    for (int it = 0; it < 4; it++) {
      if (dout[65536 + t * 4 + it] >= 0.f) { cl = it + 1; break; }
    }
    dout[65664 + t] = (float)cl;
  }
}

// --------------------------- setup kernels ---------------------------------
__global__ __launch_bounds__(256) void k_meanpsum(const float* __restrict__ src,
                                                  float* __restrict__ out, int rpc) {
  const int s = blockIdx.x, b = blockIdx.y, t = threadIdx.x;
  const int R = gridDim.x * rpc;
  const float4* base = (const float4*)src + (size_t)(b * R + s * rpc) * 256 + t;
  float4 acc = make_float4(0.f, 0.f, 0.f, 0.f);
#pragma unroll 4
  for (int r = 0; r < rpc; r++) {
    const float4 v = base[r * 256];
    ADD4(acc, v);
  }
  ((float4*)out)[((s * 16 + b) << 8) + t] = acc;
}

__global__ __launch_bounds__(256) void k_cbsq(const float* __restrict__ cbv,
                                              float* __restrict__ out) {
  const int c = blockIdx.x * 4 + (threadIdx.x >> 6);
  const int l = threadIdx.x & 63;
  const float4* cr = (const float4*)(cbv + (c << 10));
  float s = 0.f;
#pragma unroll
  for (int r = 0; r < 4; r++) {
    const float4 v = cr[4 * l + r];
    s += dot4(v, v);
  }
#pragma unroll
  for (int off = 32; off > 0; off >>= 1) s += __shfl_xor(s, off);
  if (l == 0) out[c] = s;
}

__global__ __launch_bounds__(256) void k_meancat(const float* __restrict__ pmp,
                                                 const float* __restrict__ lmp,
                                                 float* __restrict__ mean) {
  const int gi = blockIdx.x * 256 + threadIdx.x;
  const int b = gi >> 11, k = gi & 2047;
  float v = 0.f;
  if (k < 1024) {
    for (int s = 0; s < 64; s++) v += pmp[((s * 16 + b) << 10) + k];
    v *= (1.f / 2048.f);
  } else {
    const int kk = k - 1024;
    for (int s = 0; s < 16; s++) v += lmp[((s * 16 + b) << 10) + kk];
    v *= (1.f / 512.f);
  }
  mean[b * 2048 + k] = v;
}

__global__ __launch_bounds__(256) void k_s2b(const float* __restrict__ s2p,
                                             float* __restrict__ state) {
  const int gi = blockIdx.x * 256 + threadIdx.x;
  const int b = gi >> 10, h = gi & 1023;
  float s = 0.f;
  for (int si = 0; si < 8; si++) s += s2p[((si * 16 + b) << 10) + h];
  state[gi] = tanhf(s);
}

// ---------------------------------------------------------------------------
// workspace layout (floats); ~12.33M floats (~49.3 MB)
// ---------------------------------------------------------------------------
static constexpr int F_PMP   = 0;                    // 64*16*1024
static constexpr int F_LMP   = F_PMP   + 1048576;    // 16*16*1024
static constexpr int F_MEAN  = F_LMP   + 262144;     // 16*2048
static constexpr int F_CBSQ  = F_MEAN  + 32768;      // 8192
static constexpr int F_STATE = F_CBSQ  + 8192;       // 16*1024
static constexpr int F_S2P   = F_STATE + 16384;      // 8*16*1024
static constexpr int F_WQK   = F_S2P   + 131072;     // 1024*1024
static constexpr int F_T1    = F_WQK   + 1048576;    // 1024*1024
static constexpr int F_WFUSE = F_T1    + 1048576;    // 1024*2056
static constexpr int F_SQKCP = F_WFUSE + 2105344;    // 4*9*1025 (pad)
static constexpr int F_QS1   = F_SQKCP + 36928;      // 4*16*1024
static constexpr int F_LST   = F_QS1   + 65536;      // 128*16
static constexpr int F_CTX   = F_LST   + 2048;       // 16*1024
static constexpr int F_FWP   = F_CTX   + 16384;      // 16*16*2056
static constexpr int F_OPV   = F_FWP   + 526336;     // 16*1024
static constexpr int F_OPMAX = F_OPV   + 16384;      // u64[4096]
static constexpr int F_OPIDX = F_OPMAX + 8192;       // int[16]
static constexpr int F_GPRE  = F_OPIDX + 64;
static constexpr int F_GC    = F_GPRE  + 64;
static constexpr int F_STOPA = F_GC    + 64;
static constexpr int F_QSL   = F_STOPA + 64;         // 16*9*1024
static constexpr int F_LPS   = F_QSL   + 147456;     // 16*32*9
static constexpr int F_SSUM  = F_LPS   + 4608;       // 16*1024
static constexpr int F_K8P   = F_SSUM  + 16384;      // 16*16*1024
static constexpr int F_MS    = F_K8P   + 262144;     // 16*1024
static constexpr int F_GP    = F_MS    + 16384;      // 8*16*6144
static constexpr int F_BIG   = F_GP    + 786432;     // max(accst 2.0M, accp 4.7M)
static constexpr int F_END   = F_BIG   + 4718592;

static SG baseSG() {
  SG p;
  p.Bm = nullptr; p.Bg = nullptr; p.a0 = nullptr; p.out = nullptr;
  p.M = 16; p.N = 1024; p.Ncore = 1024;
  p.NB = 16; p.kslice = 64; p.ksh = 6;
  p.lda = 1024; p.ldb = 1024; p.ldo = 1024;
  p.mr = 4; p.scale = 1.f;
  return p;
}

extern "C" void kernel_launch(void* const* d_in, const int* in_sizes, int n_in,
                              void* d_out, int out_size, void* d_ws, size_t ws_size,
                              hipStream_t stream) {
  (void)in_sizes; (void)n_in; (void)out_size; (void)ws_size;
  const float* logic  = (const float*)d_in[0];
  const float* prompt = (const float*)d_in[1];
  const float* cbv    = (const float*)d_in[2];
  const float* W_init = (const float*)d_in[3];
  const float* W_pq   = (const float*)d_in[4];
  const float* W_pk   = (const float*)d_in[5];
  const float* W_pv   = (const float*)d_in[6];
  const float* slotq  = (const float*)d_in[7];
  const float* W_sq   = (const float*)d_in[8];
  const float* W_op   = (const float*)d_in[9];
  const float* W_gate = (const float*)d_in[10];
  const float* b_gate = (const float*)d_in[11];
  const float* W_stop = (const float*)d_in[12];
  const float* b_stop = (const float*)d_in[13];
  const float* Wih    = (const float*)d_in[14];
  const float* Whh    = (const float*)d_in[15];
  const float* bih    = (const float*)d_in[16];
  const float* bhh    = (const float*)d_in[17];
  float* out = (float*)d_out;
  float* w = (float*)d_ws;

  const float inv32 = 1.0f / 32.0f;

  // ---- setup ----
  k_meanpsum<<<dim3(64, 16), 256, 0, stream>>>(prompt, w + F_PMP, 32);
  k_meanpsum<<<dim3(16, 16), 256, 0, stream>>>(logic, w + F_LMP, 32);
  k_cbsq<<<2048, 256, 0, stream>>>(cbv, w + F_CBSQ);
  k_meancat<<<128, 256, 0, stream>>>(w + F_PMP, w + F_LMP, w + F_MEAN);
  {
    SG p = baseSG();
    p.a0 = w + F_MEAN; p.Bm = W_init; p.out = w + F_S2P;
    p.kslice = 256; p.ksh = 8; p.lda = 2048; p.NB = 16;  // KSg=8 -> 128 blocks
    k_sgemm<<<128, 256, 0, stream>>>(p);
  }
  k_s2b<<<64, 256, 0, stream>>>(w + F_S2P, w + F_STATE);
  // Wqk = W_pq@W_pk^T/32 ; T1 = W_sq@W_pk^T/32
  k_wgemmT<<<512, 256, 0, stream>>>(W_pq, W_pk, w + F_WQK, W_sq, w + F_T1, inv32);
  // sqkcP = slotq @ [T1 | W_gate]  (4 psums, M=9, N=1025)
  {
    SG p = baseSG();
    p.a0 = slotq; p.Bm = w + F_T1; p.Bg = W_gate;
    p.M = 9; p.N = 1025; p.Ncore = 1024; p.NB = 17;
    p.kslice = 256; p.ksh = 8; p.out = w + F_SQKCP; p.ldo = 1025; p.mr = 7;
    k_sgemm<<<68, 256, 0, stream>>>(p);
  }
  // Wfuse = W_pv @ [W_op | T1 | W_gate | W_stop_top]
  k_wgemmF<<<528, 256, 0, stream>>>(W_pv, W_op, w + F_T1, W_gate, W_stop, w + F_WFUSE);

  for (int it = 0; it < 4; ++it) {
    // qs1P = state @ Wqk (4 psums)
    {
      SG p = baseSG();
      p.a0 = w + F_STATE; p.Bm = w + F_WQK; p.out = w + F_QS1;
      p.kslice = 256; p.ksh = 8; p.NB = 16;
      k_sgemm<<<64, 256, 0, stream>>>(p);
    }
    // flash state attention (128 chunks, inline q-psum combine)
    k_flash_state<<<dim3(32, 16), 256, 0, stream>>>(prompt, w + F_QS1, w + F_BIG, w + F_LST);
    k_cst<<<256, 256, 0, stream>>>(w + F_BIG, w + F_LST, w + F_CTX);
    // fw = ctx @ Wfuse  (16 psums, N=2050)
    k_fw<<<528, 256, 0, stream>>>(w + F_CTX, w + F_WFUSE, w + F_FWP);
    // combine: opv, qsl, gate/stop scalars
    k_combw<<<641, 256, 0, stream>>>(w + F_FWP, w + F_SQKCP, w + F_OPV, w + F_QSL,
                                     w + F_GPRE, w + F_GC, w + F_STOPA);
    // codebook argmax partials + fused slot attention (one dispatch)
    k_cbslot<<<768, 256, 0, stream>>>(w + F_OPV, cbv, w + F_CBSQ,
                                      (unsigned long long*)(w + F_OPMAX),
                                      prompt, w + F_QSL, w + F_BIG, w + F_LPS);
    // K7: mask + masked mean (+ argmax finish)
    k_k7<<<65, 256, 0, stream>>>(w + F_BIG, w + F_LPS, w + F_GPRE, w + F_GC, b_gate,
                                 (const unsigned long long*)(w + F_OPMAX),
                                 (int*)(w + F_OPIDX), w + F_SSUM);
    // k8pP = ssum @ W_pv (16 psums)
    {
      SG p = baseSG();
      p.a0 = w + F_SSUM; p.Bm = W_pv; p.out = w + F_K8P;
      k_sgemm<<<256, 256, 0, stream>>>(p);
    }
    // GRU GEMM with fused ms A-stage (writes ms + d_out summary)
    k_gru<<<768, 256, 0, stream>>>(w + F_K8P, (const int*)(w + F_OPIDX), cbv,
                                   w + F_STATE, Wih, Whh, w + F_GP, w + F_MS, out, it);
    // GRU finish + stop logits/probs
    k_k9b<<<68, 256, 0, stream>>>(w + F_GP, bih, bhh, w + F_STATE, w + F_STOPA,
                                  w + F_MS, W_stop, b_stop, out, it);
  }
  k_k10<<<1, 64, 0, stream>>>(out);
}

// Round 6
// 1065.510 us; speedup vs baseline: 1.1119x; 1.1119x over previous
//
#include <hip/hip_runtime.h>

// ---------------------------------------------------------------------------
// AutoregressiveMatrixChain on MI355X, fp32.
// R6: occupancy round. cb/slot un-merged; slotattn 512-thread blocks (8 waves
// share q-LDS); flash 256 chunks; setup GEMMs split-K (4 slices, 2048+ blocks)
// + combines; k_fw KSg=32; k_msc restored (k_gru A-stage was 48x redundant).
// Workspace union-aliased (accst/accp/wgemm-psums) -> 48.4 MB.
// ---------------------------------------------------------------------------

#define DINL __device__ __forceinline__

struct SG {
  const float* Bm;   // weight [K][N]
  const float* Bg;   // extra single column for n >= Ncore
  const float* a0;   // A source
  float* out;        // psums [KSg][M][ldo]
  int M, N, Ncore, NB, kslice, ksh, lda, ldb, ldo, mr;
  float scale;
};

DINL float dot4(float4 a, float4 b) {
  return fmaf(a.x, b.x, fmaf(a.y, b.y, fmaf(a.z, b.z, a.w * b.w)));
}
DINL unsigned sortable(float f) {
  unsigned u = __float_as_uint(f);
  return (u & 0x80000000u) ? ~u : (u | 0x80000000u);
}
#define AXPY4(A, W, P) \
  { A.x = fmaf(W, P.x, A.x); A.y = fmaf(W, P.y, A.y); A.z = fmaf(W, P.z, A.z); A.w = fmaf(W, P.w, A.w); }
#define ADD4(A, V) { A.x += V.x; A.y += V.y; A.z += V.z; A.w += V.w; }

// ---------------------------------------------------------------------------
// small GEMM: out[ks][m][n] = A[m,kslice]*B[kslice,n]*scale  (A raw)
// ---------------------------------------------------------------------------
template <int MR>
DINL void sgemm_body(const SG p, int bx, float* As) {
  const int t = threadIdx.x;
  const int ks = bx / p.NB, nb = bx % p.NB;
  const int kslice = p.kslice;
  const int kb = ks * kslice;

  const int tot = p.M * kslice;
  for (int idx = t; idx < tot; idx += 256) {
    const int m = idx >> p.ksh;
    const int kl = idx & (kslice - 1);
    As[(m << p.ksh) + kl] = p.a0[m * p.lda + kb + kl];
  }
  __syncthreads();

  const int nl = t & 63, mg = t >> 6;
  const int n = nb * 64 + nl;
  const bool nok = (n < p.N);
  float acc[MR];
#pragma unroll
  for (int i = 0; i < MR; i++) acc[i] = 0.f;

  const bool useg = nok && (n >= p.Ncore);
  const float* Bc = p.Bm + n;
  for (int k4 = 0; k4 < kslice; k4 += 4) {
    float bv[4];
#pragma unroll
    for (int u = 0; u < 4; u++) {
      bv[u] = 0.f;
      if (nok) bv[u] = useg ? p.Bg[kb + k4 + u] : Bc[(kb + k4 + u) * p.ldb];
    }
#pragma unroll
    for (int i = 0; i < MR; i++) {
      const int m = mg + 4 * i;
      if (MR == 4 || m < p.M) {
        const float4 av = *(const float4*)&As[(m << p.ksh) + k4];
        acc[i] = fmaf(av.x, bv[0], acc[i]);
        acc[i] = fmaf(av.y, bv[1], acc[i]);
        acc[i] = fmaf(av.z, bv[2], acc[i]);
        acc[i] = fmaf(av.w, bv[3], acc[i]);
      }
    }
  }

  if (nok) {
#pragma unroll
    for (int i = 0; i < MR; i++) {
      const int m = mg + 4 * i;
      if (MR == 4 || m < p.M) p.out[(ks * p.M + m) * p.ldo + n] = acc[i] * p.scale;
    }
  }
}

__global__ __launch_bounds__(256) void k_sgemm(SG p) {
  __shared__ __align__(16) float As[4352];
  if (p.mr == 4) sgemm_body<4>(p, blockIdx.x, As);
  else sgemm_body<7>(p, blockIdx.x, As);
}

// ---------------------------------------------------------------------------
// setup GEMM T, split-K: psums[4] of A@B^T for (A1->C1P) and (A2->C2P).
// grid 2048 = 2 problems x 4 kslices x 256 tiles. 64x64 tile, k-major LDS.
// ---------------------------------------------------------------------------
__global__ __launch_bounds__(256) void k_wgemmT(const float* __restrict__ A1,
                                                const float* __restrict__ B,
                                                float* __restrict__ C1P,
                                                const float* __restrict__ A2,
                                                float* __restrict__ C2P) {
  __shared__ __align__(16) float As[16 * 68], Bs[16 * 68];
  const int bx = blockIdx.x;
  const int which = bx >> 10;
  const int rem = bx & 1023;
  const int ks = rem >> 8;
  const int bid = rem & 255;
  const float* A = which ? A2 : A1;
  float* CP = (which ? C2P : C1P) + ks * 1048576;
  const int bi = bid >> 4, bj = bid & 15;
  const int t = threadIdx.x;
  const int srow = t >> 2, sq = (t & 3) << 2;
  const int r0 = (t >> 4) << 2, c0 = (t & 15) << 2;
  float acc[4][4];
#pragma unroll
  for (int i = 0; i < 4; i++)
#pragma unroll
    for (int j = 0; j < 4; j++) acc[i][j] = 0.f;

  const float* Arow = A + (bi * 64 + srow) * 1024 + sq;
  const float* Brow = B + (bj * 64 + srow) * 1024 + sq;
  const int kend = ks * 256 + 256;
  for (int k0 = ks * 256; k0 < kend; k0 += 16) {
    const float4 av = *(const float4*)(Arow + k0);
    const float4 bv = *(const float4*)(Brow + k0);
    __syncthreads();
    As[(sq + 0) * 68 + srow] = av.x; As[(sq + 1) * 68 + srow] = av.y;
    As[(sq + 2) * 68 + srow] = av.z; As[(sq + 3) * 68 + srow] = av.w;
    Bs[(sq + 0) * 68 + srow] = bv.x; Bs[(sq + 1) * 68 + srow] = bv.y;
    Bs[(sq + 2) * 68 + srow] = bv.z; Bs[(sq + 3) * 68 + srow] = bv.w;
    __syncthreads();
#pragma unroll
    for (int kk = 0; kk < 16; kk++) {
      const float4 a4 = *(const float4*)&As[kk * 68 + r0];
      const float4 b4 = *(const float4*)&Bs[kk * 68 + c0];
      acc[0][0] = fmaf(a4.x, b4.x, acc[0][0]); acc[0][1] = fmaf(a4.x, b4.y, acc[0][1]);
      acc[0][2] = fmaf(a4.x, b4.z, acc[0][2]); acc[0][3] = fmaf(a4.x, b4.w, acc[0][3]);
      acc[1][0] = fmaf(a4.y, b4.x, acc[1][0]); acc[1][1] = fmaf(a4.y, b4.y, acc[1][1]);
      acc[1][2] = fmaf(a4.y, b4.z, acc[1][2]); acc[1][3] = fmaf(a4.y, b4.w, acc[1][3]);
      acc[2][0] = fmaf(a4.z, b4.x, acc[2][0]); acc[2][1] = fmaf(a4.z, b4.y, acc[2][1]);
      acc[2][2] = fmaf(a4.z, b4.z, acc[2][2]); acc[2][3] = fmaf(a4.z, b4.w, acc[2][3]);
      acc[3][0] = fmaf(a4.w, b4.x, acc[3][0]); acc[3][1] = fmaf(a4.w, b4.y, acc[3][1]);
      acc[3][2] = fmaf(a4.w, b4.z, acc[3][2]); acc[3][3] = fmaf(a4.w, b4.w, acc[3][3]);
    }
  }
#pragma unroll
  for (int i = 0; i < 4; i++) {
    const float4 v = make_float4(acc[i][0], acc[i][1], acc[i][2], acc[i][3]);
    *(float4*)&CP[(bi * 64 + r0 + i) * 1024 + bj * 64 + c0] = v;
  }
}

// combine T psums: Wqk/T1[i] = scale * sum_ks P[ks][i].  grid 8192.
__global__ __launch_bounds__(256) void k_combT(const float* __restrict__ C1P,
                                               const float* __restrict__ C2P,
                                               float* __restrict__ C1,
                                               float* __restrict__ C2, float scale) {
  const int bx = blockIdx.x;
  const int half = bx >> 12;
  const int i = ((bx & 4095) << 8) + threadIdx.x;
  const float* src = half ? C2P : C1P;
  float s = 0.f;
#pragma unroll
  for (int ks = 0; ks < 4; ks++) s += src[ks * 1048576 + i];
  (half ? C2 : C1)[i] = s * scale;
}

// ---------------------------------------------------------------------------
// setup GEMM F, split-K: WfuseP[4][1024][2056] = Wpv @ [Wop|T1|Wgate|Wstop].
// grid 2112 = 4 ks x 16 bi x 33 bj.
// ---------------------------------------------------------------------------
__global__ __launch_bounds__(256) void k_wgemmF(const float* __restrict__ Wpv,
                                                const float* __restrict__ Wop,
                                                const float* __restrict__ T1,
                                                const float* __restrict__ Wgate,
                                                const float* __restrict__ Wstop,
                                                float* __restrict__ CfP) {
  __shared__ __align__(16) float As[16 * 68], Bs[16 * 68];
  const int bx = blockIdx.x;
  const int ks = bx / 528;
  const int rem = bx % 528;
  const int bi = rem / 33, bj = rem % 33;
  float* Cf = CfP + ks * 2105344;
  const int t = threadIdx.x;
  const int srow = t >> 2, sq = (t & 3) << 2;
  const int skk = t >> 4, snq = (t & 15) << 2;
  const int r0 = (t >> 4) << 2, c0 = (t & 15) << 2;
  float acc[4][4];
#pragma unroll
  for (int i = 0; i < 4; i++)
#pragma unroll
    for (int j = 0; j < 4; j++) acc[i][j] = 0.f;

  const float* Arow = Wpv + (bi * 64 + srow) * 1024 + sq;
  const int kend = ks * 256 + 256;
  for (int k0 = ks * 256; k0 < kend; k0 += 16) {
    const float4 av = *(const float4*)(Arow + k0);
    float4 bv;
    if (bj < 16) {
      bv = *(const float4*)&Wop[(k0 + skk) * 1024 + bj * 64 + snq];
    } else if (bj < 32) {
      bv = *(const float4*)&T1[(k0 + skk) * 1024 + (bj - 16) * 64 + snq];
    } else {
      float b0 = 0.f, b1 = 0.f;
      if (snq == 0) { b0 = Wgate[k0 + skk]; b1 = Wstop[k0 + skk]; }
      bv = make_float4(b0, b1, 0.f, 0.f);
    }
    __syncthreads();
    As[(sq + 0) * 68 + srow] = av.x; As[(sq + 1) * 68 + srow] = av.y;
    As[(sq + 2) * 68 + srow] = av.z; As[(sq + 3) * 68 + srow] = av.w;
    *(float4*)&Bs[skk * 68 + snq] = bv;
    __syncthreads();
#pragma unroll
    for (int kk = 0; kk < 16; kk++) {
      const float4 a4 = *(const float4*)&As[kk * 68 + r0];
      const float4 b4 = *(const float4*)&Bs[kk * 68 + c0];
      acc[0][0] = fmaf(a4.x, b4.x, acc[0][0]); acc[0][1] = fmaf(a4.x, b4.y, acc[0][1]);
      acc[0][2] = fmaf(a4.x, b4.z, acc[0][2]); acc[0][3] = fmaf(a4.x, b4.w, acc[0][3]);
      acc[1][0] = fmaf(a4.y, b4.x, acc[1][0]); acc[1][1] = fmaf(a4.y, b4.y, acc[1][1]);
      acc[1][2] = fmaf(a4.y, b4.z, acc[1][2]); acc[1][3] = fmaf(a4.y, b4.w, acc[1][3]);
      acc[2][0] = fmaf(a4.z, b4.x, acc[2][0]); acc[2][1] = fmaf(a4.z, b4.y, acc[2][1]);
      acc[2][2] = fmaf(a4.z, b4.z, acc[2][2]); acc[2][3] = fmaf(a4.z, b4.w, acc[2][3]);
      acc[3][0] = fmaf(a4.w, b4.x, acc[3][0]); acc[3][1] = fmaf(a4.w, b4.y, acc[3][1]);
      acc[3][2] = fmaf(a4.w, b4.z, acc[3][2]); acc[3][3] = fmaf(a4.w, b4.w, acc[3][3]);
    }
  }
#pragma unroll
  for (int i = 0; i < 4; i++) {
    const int row = bi * 64 + r0 + i;
    if (bj < 32) {
      const float4 v = make_float4(acc[i][0], acc[i][1], acc[i][2], acc[i][3]);
      *(float4*)&Cf[row * 2056 + bj * 64 + c0] = v;
    } else if (c0 == 0) {
      Cf[row * 2056 + 2048] = acc[i][0];
      Cf[row * 2056 + 2049] = acc[i][1];
    }
  }
}

// combine F psums. grid 8224 (covers 1024*2056 exactly).
__global__ __launch_bounds__(256) void k_combF(const float* __restrict__ CfP,
                                               float* __restrict__ Cf) {
  const int i = (blockIdx.x << 8) + threadIdx.x;
  float s = 0.f;
#pragma unroll
  for (int ks = 0; ks < 4; ks++) s += CfP[ks * 2105344 + i];
  Cf[i] = s;
}

// ---------------------------------------------------------------------------
// per-iter wide GEMM: fwP = ctx @ Wfuse (N=2050). KSg=32, NB=33 -> 1056 blocks
// ---------------------------------------------------------------------------
__global__ __launch_bounds__(256) void k_fw(const float* __restrict__ ctx,
                                            const float* __restrict__ wfuse,
                                            float* __restrict__ outp) {
  __shared__ float As[512];
  const int t = threadIdx.x;
  const int ks = blockIdx.x / 33, nb = blockIdx.x % 33;
  const int kb = ks * 32;
  for (int idx = t; idx < 512; idx += 256) {
    As[idx] = ctx[((idx >> 5) << 10) + kb + (idx & 31)];
  }
  __syncthreads();
  const int nl = t & 63, mg = t >> 6;
  const int n = nb * 64 + nl;
  const bool nok = (n < 2050);
  const float* Bc = wfuse + n;
  float acc[4] = {0.f, 0.f, 0.f, 0.f};
  for (int k4 = 0; k4 < 32; k4 += 4) {
    float bv[4];
#pragma unroll
    for (int u = 0; u < 4; u++) bv[u] = nok ? Bc[(kb + k4 + u) * 2056] : 0.f;
#pragma unroll
    for (int i = 0; i < 4; i++) {
      const float4 av = *(const float4*)&As[((mg + 4 * i) << 5) + k4];
      acc[i] = fmaf(av.x, bv[0], acc[i]);
      acc[i] = fmaf(av.y, bv[1], acc[i]);
      acc[i] = fmaf(av.z, bv[2], acc[i]);
      acc[i] = fmaf(av.w, bv[3], acc[i]);
    }
  }
  if (nok) {
#pragma unroll
    for (int i = 0; i < 4; i++) outp[(ks * 16 + mg + 4 * i) * 2056 + n] = acc[i];
  }
}

// ---------------------------------------------------------------------------
// combine FW psums (P=32): opv (0..63), qsl (64..639), scalars (640)
// ---------------------------------------------------------------------------
__global__ __launch_bounds__(256) void k_combw(const float* __restrict__ fwP,
                                               const float* __restrict__ sqkcP,
                                               float* __restrict__ opv,
                                               float* __restrict__ qsl,
                                               float* __restrict__ gpre,
                                               float* __restrict__ gc,
                                               float* __restrict__ stopA) {
  const int bx = blockIdx.x;
  const int t = threadIdx.x;
  if (bx < 64) {
    const int i = bx * 256 + t;
    const int b = i >> 10, h = i & 1023;
    float s = 0.f;
    for (int p = 0; p < 32; p++) s += fwP[(p * 16 + b) * 2056 + h];
    opv[i] = s;
  } else if (bx < 640) {
    const int i = (bx - 64) * 256 + t;   // < 147456
    const int h = i & 1023;
    const int r = i >> 10;
    const int b = r / 9, j = r - b * 9;
    float s = 0.f;
    for (int p = 0; p < 32; p++) s += fwP[(p * 16 + b) * 2056 + 1024 + h];
    for (int sp = 0; sp < 4; sp++) s += sqkcP[(sp * 9 + j) * 1025 + h];
    qsl[i] = s;
  } else {
    if (t < 16) {
      float g = 0.f, sa = 0.f;
      for (int p = 0; p < 32; p++) {
        g += fwP[(p * 16 + t) * 2056 + 2048];
        sa += fwP[(p * 16 + t) * 2056 + 2049];
      }
      gpre[t] = g;
      stopA[t] = sa;
    } else if (t < 25) {
      const int j = t - 16;
      float g = 0.f;
      for (int sp = 0; sp < 4; sp++) g += sqkcP[(sp * 9 + j) * 1025 + 1024];
      gc[j] = g;
    }
  }
}

// ---------------------------------------------------------------------------
// codebook argmax partials: 512 blocks x 16 codes. packed-u64 max.
// ---------------------------------------------------------------------------
__global__ __launch_bounds__(256) void k_cb(const float* __restrict__ opv,
                                            const float* __restrict__ cbv,
                                            const float* __restrict__ cbsqv,
                                            unsigned long long* __restrict__ opmaxp) {
  __shared__ __align__(16) char smem[65536];
  const int bx2 = blockIdx.x;
  const int t = threadIdx.x;
  for (int idx = t; idx < 16384; idx += 256) {
    const int x = idx << 2;
    *(float*)(smem + (x ^ (((x >> 7) & 7) << 4))) = opv[idx];
  }
  __syncthreads();
  const int w = t >> 6, l = t & 63;
  const int bxl = 64 * l;
  const int key = ((bxl >> 7) & 7) << 4;
  const int o0 = bxl ^ key, o1 = (bxl + 16) ^ key, o2 = (bxl + 32) ^ key, o3 = (bxl + 48) ^ key;
  unsigned long long bk[16];
#pragma unroll
  for (int m = 0; m < 16; m++) bk[m] = 0ull;
  const int cbase = (bx2 << 4) + (w << 2);
  for (int ci = 0; ci < 4; ci++) {
    const int c = cbase + ci;
    const float4* cr = (const float4*)(cbv + (c << 10));
    const float4 c0 = cr[4 * l], c1 = cr[4 * l + 1], c2 = cr[4 * l + 2], c3 = cr[4 * l + 3];
    float sm[16];
#pragma unroll
    for (int m = 0; m < 16; m++) {
      const char* qp = smem + (m << 12);
      const float4 a0 = *(const float4*)(qp + o0);
      const float4 a1 = *(const float4*)(qp + o1);
      const float4 a2 = *(const float4*)(qp + o2);
      const float4 a3 = *(const float4*)(qp + o3);
      sm[m] = dot4(a0, c0) + dot4(a1, c1) + dot4(a2, c2) + dot4(a3, c3);
    }
#pragma unroll
    for (int off = 32; off > 0; off >>= 1) {
#pragma unroll
      for (int m = 0; m < 16; m++) sm[m] += __shfl_xor(sm[m], off);
    }
    const float cq = cbsqv[c];
#pragma unroll
    for (int m = 0; m < 16; m++) {
      const float sc = fmaf(2.f, sm[m], -cq);
      const unsigned long long k2 = ((unsigned long long)sortable(sc) << 32) | (unsigned)(8192 - c);
      bk[m] = k2 > bk[m] ? k2 : bk[m];
    }
  }
  __syncthreads();
  unsigned long long* red = (unsigned long long*)smem;
  if (l == 0) {
#pragma unroll
    for (int m = 0; m < 16; m++) red[w * 16 + m] = bk[m];
  }
  __syncthreads();
  if (t < 16) {
    unsigned long long b2 = red[t];
    for (int ww = 1; ww < 4; ww++) {
      const unsigned long long v = red[ww * 16 + t];
      b2 = v > b2 ? v : b2;
    }
    opmaxp[bx2 * 16 + t] = b2;
  }
}

// ---------------------------------------------------------------------------
// fused slot attention: 512 threads (8 waves share q-LDS), 64 keys/block,
// grid (32,16). phase1: scores+exp (wave w: 8 keys); phase2: PV (wave w:
// 128-col float2 slice). accp psums [32][16][9][1024].
// ---------------------------------------------------------------------------
__global__ __launch_bounds__(512) void k_slotattn(const float* __restrict__ prompt,
                                                  const float* __restrict__ qsl,
                                                  float* __restrict__ accp,
                                                  float* __restrict__ lpsum) {
  __shared__ __align__(16) char qsm[36864];
  __shared__ float wl[64 * 9];
  __shared__ float lred[8 * 9];
  const int b = blockIdx.y, kc = blockIdx.x;
  const int t = threadIdx.x;
  for (int idx = t; idx < 9216; idx += 512) {
    const int x = idx << 2;
    *(float*)(qsm + (x ^ (((x >> 7) & 7) << 4))) = qsl[b * 9216 + idx];
  }
  __syncthreads();
  const int w = t >> 6, l = t & 63;
  const int bxl = 64 * l;
  const int key = ((bxl >> 7) & 7) << 4;
  const int o0 = bxl ^ key, o1 = (bxl + 16) ^ key, o2 = (bxl + 32) ^ key, o3 = (bxl + 48) ^ key;
  const int k0 = kc * 64 + w * 8;
  float lacc = 0.f;
  const float* pbase = prompt + ((b * 2048 + k0) << 10) + 16 * l;
  for (int ki = 0; ki < 8; ki++) {
    const float4* pr = (const float4*)(pbase + (ki << 10));
    const float4 p0 = pr[0], p1 = pr[1], p2 = pr[2], p3 = pr[3];
    float sj[9];
#pragma unroll
    for (int j = 0; j < 9; j++) {
      const char* qp = qsm + (j << 12);
      sj[j] = dot4(*(const float4*)(qp + o0), p0) + dot4(*(const float4*)(qp + o1), p1) +
              dot4(*(const float4*)(qp + o2), p2) + dot4(*(const float4*)(qp + o3), p3);
    }
#pragma unroll
    for (int off = 32; off > 0; off >>= 1) {
#pragma unroll
      for (int j = 0; j < 9; j++) sj[j] += __shfl_xor(sj[j], off);
    }
    float wv = sj[0];
#pragma unroll
    for (int j = 1; j < 9; j++)
      if (l == j) wv = sj[j];
    if (l < 9) {
      const float e = __expf(wv);
      wl[(w * 8 + ki) * 9 + l] = e;
      lacc += e;
    }
  }
  if (l < 9) lred[w * 9 + l] = lacc;
  __syncthreads();
  if (t < 9) {
    float s = 0.f;
#pragma unroll
    for (int ww = 0; ww < 8; ww++) s += lred[ww * 9 + t];
    lpsum[(b * 32 + kc) * 9 + t] = s;
  }
  // phase 2: PV, wave w covers cols [w*128, w*128+128), float2/lane
  const int h2 = (w << 7) + (l << 1);
  float2 acc[9];
#pragma unroll
  for (int j = 0; j < 9; j++) acc[j] = make_float2(0.f, 0.f);
  const float* pb2 = prompt + ((b * 2048 + kc * 64) << 10) + h2;
#pragma unroll 4
  for (int k = 0; k < 64; k++) {
    const float2 pv = *(const float2*)(pb2 + (k << 10));
    const float* wr = &wl[k * 9];
#pragma unroll
    for (int j = 0; j < 9; j++) {
      acc[j].x = fmaf(wr[j], pv.x, acc[j].x);
      acc[j].y = fmaf(wr[j], pv.y, acc[j].y);
    }
  }
  float* ob = accp + (((kc * 16 + b) * 9) << 10) + h2;
#pragma unroll
  for (int j = 0; j < 9; j++) *(float2*)(ob + (j << 10)) = acc[j];
}

// ---------------------------------------------------------------------------
// flash attention, state pass: 256 chunks of 8 keys, grid (64,16).
// inline 4-psum q combine.
// ---------------------------------------------------------------------------
__global__ __launch_bounds__(256) void k_flash_state(const float* __restrict__ prompt,
                                                     const float* __restrict__ qs1P,
                                                     float* __restrict__ accst,
                                                     float* __restrict__ lst) {
  const int b = blockIdx.y;
  const int w = threadIdx.x >> 6, l = threadIdx.x & 63;
  const int chunk = blockIdx.x * 4 + w;  // 0..255
  float4 q0 = make_float4(0.f, 0.f, 0.f, 0.f), q1 = q0, q2 = q0, q3 = q0;
#pragma unroll
  for (int s = 0; s < 4; s++) {
    const float4* qp = (const float4*)(qs1P + ((s * 16 + b) << 10) + 16 * l);
    ADD4(q0, qp[0]); ADD4(q1, qp[1]); ADD4(q2, qp[2]); ADD4(q3, qp[3]);
  }
  float4 acc[4];
#pragma unroll
  for (int r = 0; r < 4; r++) acc[r] = make_float4(0.f, 0.f, 0.f, 0.f);
  float lsum = 0.f;
  const float* pbase = prompt + ((b * 2048 + chunk * 8) << 10) + 16 * l;
#pragma unroll 2
  for (int k = 0; k < 8; k++) {
    const float4* pr = (const float4*)(pbase + (k << 10));
    const float4 p0 = pr[0], p1 = pr[1], p2 = pr[2], p3 = pr[3];
    float s = dot4(q0, p0) + dot4(q1, p1) + dot4(q2, p2) + dot4(q3, p3);
#pragma unroll
    for (int off = 32; off > 0; off >>= 1) s += __shfl_xor(s, off);
    const float wgt = __expf(s);
    lsum += wgt;
    AXPY4(acc[0], wgt, p0); AXPY4(acc[1], wgt, p1);
    AXPY4(acc[2], wgt, p2); AXPY4(acc[3], wgt, p3);
  }
  float* ob = accst + ((chunk * 16 + b) << 10) + 16 * l;
#pragma unroll
  for (int r = 0; r < 4; r++) ((float4*)ob)[r] = acc[r];
  if (l == 0) lst[chunk * 16 + b] = lsum;
}

// combine state flash psums (256 chunks): ctx[b][h]. grid 256.
__global__ __launch_bounds__(256) void k_cst(const float* __restrict__ accst,
                                             const float* __restrict__ lst,
                                             float* __restrict__ ctx) {
  __shared__ float4 sred[256];
  __shared__ float rinv;
  const int bx = blockIdx.x;
  const int b = bx >> 4, hq = bx & 15;
  const int t = threadIdx.x;
  if (t < 64) {
    float s = 0.f;
    for (int c = t; c < 256; c += 64) s += lst[c * 16 + b];
#pragma unroll
    for (int off = 32; off > 0; off >>= 1) s += __shfl_xor(s, off);
    if (t == 0) rinv = 1.f / s;
  }
  const int h4 = hq * 16 + (t & 15);
  const int cp = t >> 4;
  float4 a = make_float4(0.f, 0.f, 0.f, 0.f);
#pragma unroll
  for (int ci = 0; ci < 16; ci++) {
    const int c = cp * 16 + ci;
    const float4 v = ((const float4*)accst)[((c * 16 + b) << 8) + h4];
    ADD4(a, v);
  }
  sred[t] = a;
  __syncthreads();
  if (t < 16) {
    float4 s = sred[t];
    for (int p2 = 1; p2 < 16; p2++) {
      const float4 v = sred[p2 * 16 + t];
      ADD4(s, v);
    }
    s.x *= rinv; s.y *= rinv; s.z *= rinv; s.w *= rinv;
    ((float4*)ctx)[(b << 8) + hq * 16 + t] = s;
  }
}

// ---------------------------------------------------------------------------
// K7: mask + masked mean (blocks 0..63); block 64: argmax finish (512 chunks)
// ---------------------------------------------------------------------------
__global__ __launch_bounds__(256) void k_k7(const float* __restrict__ accp,
                                            const float* __restrict__ lpsum,
                                            const float* __restrict__ gpre_g,
                                            const float* __restrict__ gc_g,
                                            const float* __restrict__ bgate,
                                            const unsigned long long* __restrict__ opmax,
                                            int* __restrict__ opidx,
                                            float* __restrict__ ssum) {
  __shared__ unsigned long long red[256];
  __shared__ float rl[9];
  __shared__ float gpre[16];
  __shared__ float gcs[9];
  __shared__ int mask_s[9];
  __shared__ float cntInv;
  const int bx = blockIdx.x;
  const int t = threadIdx.x;
  if (bx == 64) {
    const int b = t & 15, part = t >> 4;
    unsigned long long best = 0ull;
    for (int c = part * 32; c < part * 32 + 32; c++) {
      const unsigned long long v = opmax[c * 16 + b];
      best = v > best ? v : best;
    }
    red[t] = best;
    __syncthreads();
    if (t < 16) {
      unsigned long long m = red[t];
      for (int p2 = 1; p2 < 16; p2++) {
        const unsigned long long v = red[p2 * 16 + t];
        m = v > m ? v : m;
      }
      opidx[t] = 8192 - (int)(unsigned)(m & 0xFFFFFFFFull);
    }
    return;
  }
  const int b = bx >> 2;
  if (t < 9) {
    float s = 0.f;
    for (int c = 0; c < 32; c++) s += lpsum[(b * 32 + c) * 9 + t];
    rl[t] = 1.f / s;
  }
  if (t >= 32 && t < 48) gpre[t - 32] = gpre_g[t - 32];
  if (t >= 48 && t < 57) gcs[t - 48] = gc_g[t - 48];
  __syncthreads();
  if (t == 0) {
    const float bg = bgate[0];
    bool any = false;
    for (int bb = 0; bb < 16; bb++)
      for (int j = 0; j < 9; j++)
        if (gpre[bb] + gcs[j] + bg >= 0.f) any = true;
    int cnt = 0;
    if (any) {
      for (int j = 0; j < 9; j++) {
        const int s = (gpre[b] + gcs[j] + bg >= 0.f) ? 1 : 0;
        mask_s[j] = s;
        cnt += s;
      }
    } else {
      float bv = -3.4e38f;
      int bj = 0;
      for (int j = 0; j < 9; j++) {
        const float v = gpre[b] + gcs[j] + bg;
        if (v > bv) { bv = v; bj = j; }
      }
      for (int j = 0; j < 9; j++) mask_s[j] = (j == bj) ? 1 : 0;
      cnt = 1;
    }
    cntInv = 1.f / (float)(cnt > 0 ? cnt : 1);
  }
  __syncthreads();
  const int h = ((bx & 3) << 8) + t;
  float v = 0.f;
  for (int j = 0; j < 9; j++) {
    if (mask_s[j]) {
      float s = 0.f;
      for (int c = 0; c < 32; c++) s += accp[(((c * 16 + b) * 9 + j) << 10) + h];
      v = fmaf(s, rl[j], v);
    }
  }
  ssum[(b << 10) + h] = v * cntInv;
}

// ms = tanh(sum_p k8p + codebook[opidx]); side-writes d_out summary
__global__ __launch_bounds__(256) void k_msc(const float* __restrict__ k8p,
                                             const int* __restrict__ opidx,
                                             const float* __restrict__ cbv,
                                             float* __restrict__ ms,
                                             float* __restrict__ dout, int it) {
  const int i = blockIdx.x * 256 + threadIdx.x;  // < 16384
  const int b = i >> 10, h = i & 1023;
  float s = 0.f;
  for (int p = 0; p < 16; p++) s += k8p[p * 16384 + i];
  const float v = tanhf(s + cbv[(opidx[b] << 10) + h]);
  ms[i] = v;
  dout[(b << 12) + (it << 10) + h] = v;
}

// ---------------------------------------------------------------------------
// GRU GEMM: blocks 0..383 = ms@Wih, 384..767 = state@Whh. KSg=8, kslice 128.
// ---------------------------------------------------------------------------
__global__ __launch_bounds__(256) void k_gru(const float* __restrict__ ms,
                                             const float* __restrict__ state,
                                             const float* __restrict__ Wih,
                                             const float* __restrict__ Whh,
                                             float* __restrict__ gpP) {
  __shared__ float As[2048];
  const int bx = blockIdx.x;
  const int t = threadIdx.x;
  const int half = (bx >= 384) ? 1 : 0;
  const int b2 = half ? bx - 384 : bx;
  const int ks = b2 / 48, nb = b2 % 48;
  const int kb = ks * 128;
  const float* src = half ? state : ms;
  for (int idx = t; idx < 2048; idx += 256) {
    As[idx] = src[((idx >> 7) << 10) + kb + (idx & 127)];
  }
  __syncthreads();
  const int nl = t & 63, mg = t >> 6;
  const int n = nb * 64 + nl;
  const float* Bc = (half ? Whh : Wih) + n;
  float acc[4] = {0.f, 0.f, 0.f, 0.f};
  for (int k4 = 0; k4 < 128; k4 += 4) {
    float bv[4];
#pragma unroll
    for (int u = 0; u < 4; u++) bv[u] = Bc[(kb + k4 + u) * 3072];
#pragma unroll
    for (int i = 0; i < 4; i++) {
      const float4 av = *(const float4*)&As[((mg + 4 * i) << 7) + k4];
      acc[i] = fmaf(av.x, bv[0], acc[i]);
      acc[i] = fmaf(av.y, bv[1], acc[i]);
      acc[i] = fmaf(av.z, bv[2], acc[i]);
      acc[i] = fmaf(av.w, bv[3], acc[i]);
    }
  }
  float* outp = gpP + half * 3072;
#pragma unroll
  for (int i = 0; i < 4; i++) outp[(ks * 16 + mg + 4 * i) * 6144 + n] = acc[i];
}

// ---------------------------------------------------------------------------
// K9b: GRU elementwise finish (0..63) + stop logits (64..67)
// ---------------------------------------------------------------------------
__global__ __launch_bounds__(256) void k_k9b(const float* __restrict__ gp,
                                             const float* __restrict__ bih,
                                             const float* __restrict__ bhh,
                                             float* __restrict__ state,
                                             const float* __restrict__ stopA,
                                             const float* __restrict__ ms,
                                             const float* __restrict__ Wstop,
                                             const float* __restrict__ bstop,
                                             float* __restrict__ dout, int it) {
  const int bx = blockIdx.x;
  const int t = threadIdx.x;
  if (bx < 64) {
    const int gi = bx * 256 + t;
    const int b = gi >> 10, h = gi & 1023;
    float ir = 0.f, iz = 0.f, inn = 0.f, hr = 0.f, hz = 0.f, hn = 0.f;
    for (int s = 0; s < 8; s++) {
      const float* g = gp + (s * 16 + b) * 6144;
      ir += g[h]; iz += g[1024 + h]; inn += g[2048 + h];
      hr += g[3072 + h]; hz += g[4096 + h]; hn += g[5120 + h];
    }
    ir += bih[h]; iz += bih[1024 + h]; inn += bih[2048 + h];
    hr += bhh[h]; hz += bhh[1024 + h]; hn += bhh[2048 + h];
    const float r = 1.f / (1.f + __expf(-(ir + hr)));
    const float z = 1.f / (1.f + __expf(-(iz + hz)));
    const float n = tanhf(fmaf(r, hn, inn));
    const float hold = state[gi];
    state[gi] = (1.f - z) * n + z * hold;
  } else {
    const int wid = (bx - 64) * 4 + (t >> 6);
    const int l = t & 63;
    float p = 0.f;
    for (int i = 0; i < 16; i++) {
      const int h = l + (i << 6);
      p = fmaf(ms[(wid << 10) + h], Wstop[1024 + h], p);
    }
#pragma unroll
    for (int off = 32; off > 0; off >>= 1) p += __shfl_xor(p, off);
    if (l == 0) {
      const float lg = p + stopA[wid] + bstop[0];
      dout[65536 + wid * 4 + it] = lg;
      dout[65600 + wid * 4 + it] = 1.f / (1.f + __expf(-lg));
    }
  }
}

__global__ void k_k10(float* __restrict__ dout) {
  const int t = threadIdx.x;
  if (t < 16) {
    int cl = 4;
    for (int it = 0; it < 4; it++) {
      if (dout[65536 + t * 4 + it] >= 0.f) { cl = it + 1; break; }
    }
    dout[65664 + t] = (float)cl;
  }
}

// --------------------------- setup kernels ---------------------------------
__global__ __launch_bounds__(256) void k_meanpsum(const float* __restrict__ src,
                                                  float* __restrict__ out, int rpc) {
  const int s = blockIdx.x, b = blockIdx.y, t = threadIdx.x;
  const int R = gridDim.x * rpc;
  const float4* base = (const float4*)src + (size_t)(b * R + s * rpc) * 256 + t;
  float4 acc = make_float4(0.f, 0.f, 0.f, 0.f);
#pragma unroll 4
  for (int r = 0; r < rpc; r++) {
    const float4 v = base[r * 256];
    ADD4(acc, v);
  }
  ((float4*)out)[((s * 16 + b) << 8) + t] = acc;
}

__global__ __launch_bounds__(256) void k_cbsq(const float* __restrict__ cbv,
                                              float* __restrict__ out) {
  const int c = blockIdx.x * 4 + (threadIdx.x >> 6);
  const int l = threadIdx.x & 63;
  const float4* cr = (const float4*)(cbv + (c << 10));
  float s = 0.f;
#pragma unroll
  for (int r = 0; r < 4; r++) {
    const float4 v = cr[4 * l + r];
    s += dot4(v, v);
  }
#pragma unroll
  for (int off = 32; off > 0; off >>= 1) s += __shfl_xor(s, off);
  if (l == 0) out[c] = s;
}

__global__ __launch_bounds__(256) void k_meancat(const float* __restrict__ pmp,
                                                 const float* __restrict__ lmp,
                                                 float* __restrict__ mean) {
  const int gi = blockIdx.x * 256 + threadIdx.x;
  const int b = gi >> 11, k = gi & 2047;
  float v = 0.f;
  if (k < 1024) {
    for (int s = 0; s < 64; s++) v += pmp[((s * 16 + b) << 10) + k];
    v *= (1.f / 2048.f);
  } else {
    const int kk = k - 1024;
    for (int s = 0; s < 16; s++) v += lmp[((s * 16 + b) << 10) + kk];
    v *= (1.f / 512.f);
  }
  mean[b * 2048 + k] = v;
}

__global__ __launch_bounds__(256) void k_s2b(const float* __restrict__ s2p,
                                             float* __restrict__ state) {
  const int gi = blockIdx.x * 256 + threadIdx.x;
  const int b = gi >> 10, h = gi & 1023;
  float s = 0.f;
  for (int si = 0; si < 8; si++) s += s2p[((si * 16 + b) << 10) + h];
  state[gi] = tanhf(s);
}

// ---------------------------------------------------------------------------
// workspace layout (floats), 12.69M floats = 48.4 MB, with liveness aliasing
// ---------------------------------------------------------------------------
// persistent
static constexpr int F_CBSQ  = 0;                    // 8192
static constexpr int F_STATE = 8192;                 // 16384
static constexpr int F_WQK   = 24576;                // 1048576
static constexpr int F_T1    = F_WQK + 1048576;      // 1048576
static constexpr int F_WFUSE = F_T1 + 1048576;       // 2105344
static constexpr int F_SQKCP = F_WFUSE + 2105344;    // 36928
static constexpr int F_UN    = F_SQKCP + 36928;      // union region, 8421376
// setup phase A (dead before wgemmT)
static constexpr int F_PMP   = F_UN;                 // 1048576
static constexpr int F_LMP   = F_PMP + 1048576;      // 262144
static constexpr int F_MEAN  = F_LMP + 262144;       // 32768
static constexpr int F_S2P   = F_MEAN + 32768;       // 131072
// setup phase B (psums)
static constexpr int F_WQKP  = F_UN;                 // 4194304
static constexpr int F_T1P   = F_UN + 4194304;       // 4194304
// setup phase C
static constexpr int F_WFP   = F_UN;                 // 8421376
// per-iter
static constexpr int F_QS1   = F_UN;                 // 65536
static constexpr int F_LST   = F_QS1 + 65536;        // 4096
static constexpr int F_CTX   = F_LST + 4096;         // 16384
static constexpr int F_FWP   = F_CTX + 16384;        // 32*16*2056 = 1052672
static constexpr int F_OPV   = F_FWP + 1052672;      // 16384
static constexpr int F_OPMAX = F_OPV + 16384;        // u64[8192] = 16384 floats
static constexpr int F_OPIDX = F_OPMAX + 16384;      // 64
static constexpr int F_GPRE  = F_OPIDX + 64;         // 64
static constexpr int F_GC    = F_GPRE + 64;          // 64
static constexpr int F_STOPA = F_GC + 64;            // 64
static constexpr int F_QSL   = F_STOPA + 64;         // 147456
static constexpr int F_LPS   = F_QSL + 147456;       // 4672
static constexpr int F_SSUM  = F_LPS + 4672;         // 16384
static constexpr int F_MS    = F_SSUM + 16384;       // 16384
static constexpr int F_GP    = F_MS + 16384;         // 786432
static constexpr int F_K8P   = F_GP + 786432;        // 262144
static constexpr int F_BIG   = F_K8P + 262144;       // max(accst 4.19M, accp 4.72M)
static constexpr int F_END   = F_UN + 8421376;

static SG baseSG() {
  SG p;
  p.Bm = nullptr; p.Bg = nullptr; p.a0 = nullptr; p.out = nullptr;
  p.M = 16; p.N = 1024; p.Ncore = 1024;
  p.NB = 16; p.kslice = 64; p.ksh = 6;
  p.lda = 1024; p.ldb = 1024; p.ldo = 1024;
  p.mr = 4; p.scale = 1.f;
  return p;
}

extern "C" void kernel_launch(void* const* d_in, const int* in_sizes, int n_in,
                              void* d_out, int out_size, void* d_ws, size_t ws_size,
                              hipStream_t stream) {
  (void)in_sizes; (void)n_in; (void)out_size; (void)ws_size;
  const float* logic  = (const float*)d_in[0];
  const float* prompt = (const float*)d_in[1];
  const float* cbv    = (const float*)d_in[2];
  const float* W_init = (const float*)d_in[3];
  const float* W_pq   = (const float*)d_in[4];
  const float* W_pk   = (const float*)d_in[5];
  const float* W_pv   = (const float*)d_in[6];
  const float* slotq  = (const float*)d_in[7];
  const float* W_sq   = (const float*)d_in[8];
  const float* W_op   = (const float*)d_in[9];
  const float* W_gate = (const float*)d_in[10];
  const float* b_gate = (const float*)d_in[11];
  const float* W_stop = (const float*)d_in[12];
  const float* b_stop = (const float*)d_in[13];
  const float* Wih    = (const float*)d_in[14];
  const float* Whh    = (const float*)d_in[15];
  const float* bih    = (const float*)d_in[16];
  const float* bhh    = (const float*)d_in[17];
  float* out = (float*)d_out;
  float* w = (float*)d_ws;

  const float inv32 = 1.0f / 32.0f;

  // ---- setup phase A: means + state init ----
  k_meanpsum<<<dim3(64, 16), 256, 0, stream>>>(prompt, w + F_PMP, 32);
  k_meanpsum<<<dim3(16, 16), 256, 0, stream>>>(logic, w + F_LMP, 32);
  k_cbsq<<<2048, 256, 0, stream>>>(cbv, w + F_CBSQ);
  k_meancat<<<128, 256, 0, stream>>>(w + F_PMP, w + F_LMP, w + F_MEAN);
  {
    SG p = baseSG();
    p.a0 = w + F_MEAN; p.Bm = W_init; p.out = w + F_S2P;
    p.kslice = 256; p.ksh = 8; p.lda = 2048; p.NB = 16;  // KSg=8 -> 128 blocks
    k_sgemm<<<128, 256, 0, stream>>>(p);
  }
  k_s2b<<<64, 256, 0, stream>>>(w + F_S2P, w + F_STATE);
  // ---- setup phase B: Wqk = W_pq@W_pk^T/32, T1 = W_sq@W_pk^T/32 (split-K) ----
  k_wgemmT<<<2048, 256, 0, stream>>>(W_pq, W_pk, w + F_WQKP, W_sq, w + F_T1P);
  k_combT<<<8192, 256, 0, stream>>>(w + F_WQKP, w + F_T1P, w + F_WQK, w + F_T1, inv32);
  // sqkcP = slotq @ [T1 | W_gate]  (4 psums, M=9, N=1025)
  {
    SG p = baseSG();
    p.a0 = slotq; p.Bm = w + F_T1; p.Bg = W_gate;
    p.M = 9; p.N = 1025; p.Ncore = 1024; p.NB = 17;
    p.kslice = 256; p.ksh = 8; p.out = w + F_SQKCP; p.ldo = 1025; p.mr = 7;
    k_sgemm<<<68, 256, 0, stream>>>(p);
  }
  // ---- setup phase C: Wfuse = W_pv @ [W_op | T1 | W_gate | W_stop_top] ----
  k_wgemmF<<<2112, 256, 0, stream>>>(W_pv, W_op, w + F_T1, W_gate, W_stop, w + F_WFP);
  k_combF<<<8224, 256, 0, stream>>>(w + F_WFP, w + F_WFUSE);

  for (int it = 0; it < 4; ++it) {
    // qs1P = state @ Wqk (4 psums)
    {
      SG p = baseSG();
      p.a0 = w + F_STATE; p.Bm = w + F_WQK; p.out = w + F_QS1;
      p.kslice = 256; p.ksh = 8; p.NB = 16;
      k_sgemm<<<64, 256, 0, stream>>>(p);
    }
    // flash state attention (256 chunks of 8 keys)
    k_flash_state<<<dim3(64, 16), 256, 0, stream>>>(prompt, w + F_QS1, w + F_BIG, w + F_LST);
    k_cst<<<256, 256, 0, stream>>>(w + F_BIG, w + F_LST, w + F_CTX);
    // fw = ctx @ Wfuse  (32 psums, N=2050)
    k_fw<<<1056, 256, 0, stream>>>(w + F_CTX, w + F_WFUSE, w + F_FWP);
    // combine: opv, qsl, gate/stop scalars
    k_combw<<<641, 256, 0, stream>>>(w + F_FWP, w + F_SQKCP, w + F_OPV, w + F_QSL,
                                     w + F_GPRE, w + F_GC, w + F_STOPA);
    // codebook argmax partials (512 blocks x 16 codes)
    k_cb<<<512, 256, 0, stream>>>(w + F_OPV, cbv, w + F_CBSQ,
                                  (unsigned long long*)(w + F_OPMAX));
    // fused slot attention (512 threads, 8 waves share q-LDS)
    k_slotattn<<<dim3(32, 16), 512, 0, stream>>>(prompt, w + F_QSL, w + F_BIG, w + F_LPS);
    // K7: mask + masked mean (+ argmax finish)
    k_k7<<<65, 256, 0, stream>>>(w + F_BIG, w + F_LPS, w + F_GPRE, w + F_GC, b_gate,
                                 (const unsigned long long*)(w + F_OPMAX),
                                 (int*)(w + F_OPIDX), w + F_SSUM);
    // k8pP = ssum @ W_pv (16 psums)
    {
      SG p = baseSG();
      p.a0 = w + F_SSUM; p.Bm = W_pv; p.out = w + F_K8P;
      k_sgemm<<<256, 256, 0, stream>>>(p);
    }
    // ms = tanh(op_emb + slot_summary); writes d_out summary
    k_msc<<<64, 256, 0, stream>>>(w + F_K8P, (const int*)(w + F_OPIDX), cbv,
                                  w + F_MS, out, it);
    // GRU: [ms @ Wih] + [state @ Whh] -> gp (8 psums each)
    k_gru<<<768, 256, 0, stream>>>(w + F_MS, w + F_STATE, Wih, Whh, w + F_GP);
    // GRU finish + stop logits/probs
    k_k9b<<<68, 256, 0, stream>>>(w + F_GP, bih, bhh, w + F_STATE, w + F_STOPA,
                                  w + F_MS, W_stop, b_stop, out, it);
  }
  k_k10<<<1, 64, 0, stream>>>(out);
}

// Round 7
// 1030.734 us; speedup vs baseline: 1.1494x; 1.0337x over previous
//
#include <hip/hip_runtime.h>

// ---------------------------------------------------------------------------
// AutoregressiveMatrixChain on MI355X, fp32.
// R7: slot-score decomposition. E[b][k][j] = exp(sqk_j . p_bk) precomputed
// once (iteration-invariant); per-iter slot pass needs 1 dot/key + 9 mults
// (wexp = exp(qslb.p) * E). q-LDS eliminated; combw 9x smaller; k_msc folded
// into k_gru A-stage; qs1 KSg=8.
// ---------------------------------------------------------------------------

#define DINL __device__ __forceinline__

struct SG {
  const float* Bm;   // weight [K][N]
  const float* Bg;   // extra single column for n >= Ncore
  const float* a0;   // A source
  float* out;        // psums [KSg][M][ldo]
  int M, N, Ncore, NB, kslice, ksh, lda, ldb, ldo, mr;
  float scale;
};

DINL float dot4(float4 a, float4 b) {
  return fmaf(a.x, b.x, fmaf(a.y, b.y, fmaf(a.z, b.z, a.w * b.w)));
}
DINL unsigned sortable(float f) {
  unsigned u = __float_as_uint(f);
  return (u & 0x80000000u) ? ~u : (u | 0x80000000u);
}
#define AXPY4(A, W, P) \
  { A.x = fmaf(W, P.x, A.x); A.y = fmaf(W, P.y, A.y); A.z = fmaf(W, P.z, A.z); A.w = fmaf(W, P.w, A.w); }
#define ADD4(A, V) { A.x += V.x; A.y += V.y; A.z += V.z; A.w += V.w; }

// ---------------------------------------------------------------------------
// small GEMM: out[ks][m][n] = A[m,kslice]*B[kslice,n]*scale  (A raw)
// ---------------------------------------------------------------------------
template <int MR>
DINL void sgemm_body(const SG p, int bx, float* As) {
  const int t = threadIdx.x;
  const int ks = bx / p.NB, nb = bx % p.NB;
  const int kslice = p.kslice;
  const int kb = ks * kslice;

  const int tot = p.M * kslice;
  for (int idx = t; idx < tot; idx += 256) {
    const int m = idx >> p.ksh;
    const int kl = idx & (kslice - 1);
    As[(m << p.ksh) + kl] = p.a0[m * p.lda + kb + kl];
  }
  __syncthreads();

  const int nl = t & 63, mg = t >> 6;
  const int n = nb * 64 + nl;
  const bool nok = (n < p.N);
  float acc[MR];
#pragma unroll
  for (int i = 0; i < MR; i++) acc[i] = 0.f;

  const bool useg = nok && (n >= p.Ncore);
  const float* Bc = p.Bm + n;
  for (int k4 = 0; k4 < kslice; k4 += 4) {
    float bv[4];
#pragma unroll
    for (int u = 0; u < 4; u++) {
      bv[u] = 0.f;
      if (nok) bv[u] = useg ? p.Bg[kb + k4 + u] : Bc[(kb + k4 + u) * p.ldb];
    }
#pragma unroll
    for (int i = 0; i < MR; i++) {
      const int m = mg + 4 * i;
      if (MR == 4 || m < p.M) {
        const float4 av = *(const float4*)&As[(m << p.ksh) + k4];
        acc[i] = fmaf(av.x, bv[0], acc[i]);
        acc[i] = fmaf(av.y, bv[1], acc[i]);
        acc[i] = fmaf(av.z, bv[2], acc[i]);
        acc[i] = fmaf(av.w, bv[3], acc[i]);
      }
    }
  }

  if (nok) {
#pragma unroll
    for (int i = 0; i < MR; i++) {
      const int m = mg + 4 * i;
      if (MR == 4 || m < p.M) p.out[(ks * p.M + m) * p.ldo + n] = acc[i] * p.scale;
    }
  }
}

__global__ __launch_bounds__(256) void k_sgemm(SG p) {
  __shared__ __align__(16) float As[4352];
  if (p.mr == 4) sgemm_body<4>(p, blockIdx.x, As);
  else sgemm_body<7>(p, blockIdx.x, As);
}

// ---------------------------------------------------------------------------
// setup GEMM T, split-K: psums[4] of A@B^T for (A1->C1P) and (A2->C2P).
// ---------------------------------------------------------------------------
__global__ __launch_bounds__(256) void k_wgemmT(const float* __restrict__ A1,
                                                const float* __restrict__ B,
                                                float* __restrict__ C1P,
                                                const float* __restrict__ A2,
                                                float* __restrict__ C2P) {
  __shared__ __align__(16) float As[16 * 68], Bs[16 * 68];
  const int bx = blockIdx.x;
  const int which = bx >> 10;
  const int rem = bx & 1023;
  const int ks = rem >> 8;
  const int bid = rem & 255;
  const float* A = which ? A2 : A1;
  float* CP = (which ? C2P : C1P) + ks * 1048576;
  const int bi = bid >> 4, bj = bid & 15;
  const int t = threadIdx.x;
  const int srow = t >> 2, sq = (t & 3) << 2;
  const int r0 = (t >> 4) << 2, c0 = (t & 15) << 2;
  float acc[4][4];
#pragma unroll
  for (int i = 0; i < 4; i++)
#pragma unroll
    for (int j = 0; j < 4; j++) acc[i][j] = 0.f;

  const float* Arow = A + (bi * 64 + srow) * 1024 + sq;
  const float* Brow = B + (bj * 64 + srow) * 1024 + sq;
  const int kend = ks * 256 + 256;
  for (int k0 = ks * 256; k0 < kend; k0 += 16) {
    const float4 av = *(const float4*)(Arow + k0);
    const float4 bv = *(const float4*)(Brow + k0);
    __syncthreads();
    As[(sq + 0) * 68 + srow] = av.x; As[(sq + 1) * 68 + srow] = av.y;
    As[(sq + 2) * 68 + srow] = av.z; As[(sq + 3) * 68 + srow] = av.w;
    Bs[(sq + 0) * 68 + srow] = bv.x; Bs[(sq + 1) * 68 + srow] = bv.y;
    Bs[(sq + 2) * 68 + srow] = bv.z; Bs[(sq + 3) * 68 + srow] = bv.w;
    __syncthreads();
#pragma unroll
    for (int kk = 0; kk < 16; kk++) {
      const float4 a4 = *(const float4*)&As[kk * 68 + r0];
      const float4 b4 = *(const float4*)&Bs[kk * 68 + c0];
      acc[0][0] = fmaf(a4.x, b4.x, acc[0][0]); acc[0][1] = fmaf(a4.x, b4.y, acc[0][1]);
      acc[0][2] = fmaf(a4.x, b4.z, acc[0][2]); acc[0][3] = fmaf(a4.x, b4.w, acc[0][3]);
      acc[1][0] = fmaf(a4.y, b4.x, acc[1][0]); acc[1][1] = fmaf(a4.y, b4.y, acc[1][1]);
      acc[1][2] = fmaf(a4.y, b4.z, acc[1][2]); acc[1][3] = fmaf(a4.y, b4.w, acc[1][3]);
      acc[2][0] = fmaf(a4.z, b4.x, acc[2][0]); acc[2][1] = fmaf(a4.z, b4.y, acc[2][1]);
      acc[2][2] = fmaf(a4.z, b4.z, acc[2][2]); acc[2][3] = fmaf(a4.z, b4.w, acc[2][3]);
      acc[3][0] = fmaf(a4.w, b4.x, acc[3][0]); acc[3][1] = fmaf(a4.w, b4.y, acc[3][1]);
      acc[3][2] = fmaf(a4.w, b4.z, acc[3][2]); acc[3][3] = fmaf(a4.w, b4.w, acc[3][3]);
    }
  }
#pragma unroll
  for (int i = 0; i < 4; i++) {
    const float4 v = make_float4(acc[i][0], acc[i][1], acc[i][2], acc[i][3]);
    *(float4*)&CP[(bi * 64 + r0 + i) * 1024 + bj * 64 + c0] = v;
  }
}

// combine T psums
__global__ __launch_bounds__(256) void k_combT(const float* __restrict__ C1P,
                                               const float* __restrict__ C2P,
                                               float* __restrict__ C1,
                                               float* __restrict__ C2, float scale) {
  const int bx = blockIdx.x;
  const int half = bx >> 12;
  const int i = ((bx & 4095) << 8) + threadIdx.x;
  const float* src = half ? C2P : C1P;
  float s = 0.f;
#pragma unroll
  for (int ks = 0; ks < 4; ks++) s += src[ks * 1048576 + i];
  (half ? C2 : C1)[i] = s * scale;
}

// ---------------------------------------------------------------------------
// setup GEMM F, split-K: WfuseP[4][1024][2056] = Wpv @ [Wop|T1|Wgate|Wstop].
// ---------------------------------------------------------------------------
__global__ __launch_bounds__(256) void k_wgemmF(const float* __restrict__ Wpv,
                                                const float* __restrict__ Wop,
                                                const float* __restrict__ T1,
                                                const float* __restrict__ Wgate,
                                                const float* __restrict__ Wstop,
                                                float* __restrict__ CfP) {
  __shared__ __align__(16) float As[16 * 68], Bs[16 * 68];
  const int bx = blockIdx.x;
  const int ks = bx / 528;
  const int rem = bx % 528;
  const int bi = rem / 33, bj = rem % 33;
  float* Cf = CfP + ks * 2105344;
  const int t = threadIdx.x;
  const int srow = t >> 2, sq = (t & 3) << 2;
  const int skk = t >> 4, snq = (t & 15) << 2;
  const int r0 = (t >> 4) << 2, c0 = (t & 15) << 2;
  float acc[4][4];
#pragma unroll
  for (int i = 0; i < 4; i++)
#pragma unroll
    for (int j = 0; j < 4; j++) acc[i][j] = 0.f;

  const float* Arow = Wpv + (bi * 64 + srow) * 1024 + sq;
  const int kend = ks * 256 + 256;
  for (int k0 = ks * 256; k0 < kend; k0 += 16) {
    const float4 av = *(const float4*)(Arow + k0);
    float4 bv;
    if (bj < 16) {
      bv = *(const float4*)&Wop[(k0 + skk) * 1024 + bj * 64 + snq];
    } else if (bj < 32) {
      bv = *(const float4*)&T1[(k0 + skk) * 1024 + (bj - 16) * 64 + snq];
    } else {
      float b0 = 0.f, b1 = 0.f;
      if (snq == 0) { b0 = Wgate[k0 + skk]; b1 = Wstop[k0 + skk]; }
      bv = make_float4(b0, b1, 0.f, 0.f);
    }
    __syncthreads();
    As[(sq + 0) * 68 + srow] = av.x; As[(sq + 1) * 68 + srow] = av.y;
    As[(sq + 2) * 68 + srow] = av.z; As[(sq + 3) * 68 + srow] = av.w;
    *(float4*)&Bs[skk * 68 + snq] = bv;
    __syncthreads();
#pragma unroll
    for (int kk = 0; kk < 16; kk++) {
      const float4 a4 = *(const float4*)&As[kk * 68 + r0];
      const float4 b4 = *(const float4*)&Bs[kk * 68 + c0];
      acc[0][0] = fmaf(a4.x, b4.x, acc[0][0]); acc[0][1] = fmaf(a4.x, b4.y, acc[0][1]);
      acc[0][2] = fmaf(a4.x, b4.z, acc[0][2]); acc[0][3] = fmaf(a4.x, b4.w, acc[0][3]);
      acc[1][0] = fmaf(a4.y, b4.x, acc[1][0]); acc[1][1] = fmaf(a4.y, b4.y, acc[1][1]);
      acc[1][2] = fmaf(a4.y, b4.z, acc[1][2]); acc[1][3] = fmaf(a4.y, b4.w, acc[1][3]);
      acc[2][0] = fmaf(a4.z, b4.x, acc[2][0]); acc[2][1] = fmaf(a4.z, b4.y, acc[2][1]);
      acc[2][2] = fmaf(a4.z, b4.z, acc[2][2]); acc[2][3] = fmaf(a4.z, b4.w, acc[2][3]);
      acc[3][0] = fmaf(a4.w, b4.x, acc[3][0]); acc[3][1] = fmaf(a4.w, b4.y, acc[3][1]);
      acc[3][2] = fmaf(a4.w, b4.z, acc[3][2]); acc[3][3] = fmaf(a4.w, b4.w, acc[3][3]);
    }
  }
#pragma unroll
  for (int i = 0; i < 4; i++) {
    const int row = bi * 64 + r0 + i;
    if (bj < 32) {
      const float4 v = make_float4(acc[i][0], acc[i][1], acc[i][2], acc[i][3]);
      *(float4*)&Cf[row * 2056 + bj * 64 + c0] = v;
    } else if (c0 == 0) {
      Cf[row * 2056 + 2048] = acc[i][0];
      Cf[row * 2056 + 2049] = acc[i][1];
    }
  }
}

__global__ __launch_bounds__(256) void k_combF(const float* __restrict__ CfP,
                                               float* __restrict__ Cf) {
  const int i = (blockIdx.x << 8) + threadIdx.x;
  float s = 0.f;
#pragma unroll
  for (int ks = 0; ks < 4; ks++) s += CfP[ks * 2105344 + i];
  Cf[i] = s;
}

// ---------------------------------------------------------------------------
// setup: E[b][k][9] = exp(sqk_j . p_bk). grid (32,16), 512 threads.
// sqk staged from 4 psums into swizzled LDS.
// ---------------------------------------------------------------------------
__global__ __launch_bounds__(512) void k_E(const float* __restrict__ prompt,
                                           const float* __restrict__ sqkcP,
                                           float* __restrict__ E) {
  __shared__ __align__(16) char qsm[36864];
  const int b = blockIdx.y, kc = blockIdx.x;
  const int t = threadIdx.x;
  for (int idx = t; idx < 9216; idx += 512) {
    const int j = idx >> 10, h = idx & 1023;
    float s = 0.f;
    for (int sp = 0; sp < 4; sp++) s += sqkcP[(sp * 9 + j) * 1025 + h];
    const int x = idx << 2;
    *(float*)(qsm + (x ^ (((x >> 7) & 7) << 4))) = s;
  }
  __syncthreads();
  const int w = t >> 6, l = t & 63;
  const int bxl = 64 * l;
  const int key = ((bxl >> 7) & 7) << 4;
  const int o0 = bxl ^ key, o1 = (bxl + 16) ^ key, o2 = (bxl + 32) ^ key, o3 = (bxl + 48) ^ key;
  const int k0 = kc * 64 + w * 8;
  const float* pbase = prompt + ((b * 2048 + k0) << 10) + 16 * l;
  for (int ki = 0; ki < 8; ki++) {
    const float4* pr = (const float4*)(pbase + (ki << 10));
    const float4 p0 = pr[0], p1 = pr[1], p2 = pr[2], p3 = pr[3];
    float sj[9];
#pragma unroll
    for (int j = 0; j < 9; j++) {
      const char* qp = qsm + (j << 12);
      sj[j] = dot4(*(const float4*)(qp + o0), p0) + dot4(*(const float4*)(qp + o1), p1) +
              dot4(*(const float4*)(qp + o2), p2) + dot4(*(const float4*)(qp + o3), p3);
    }
#pragma unroll
    for (int off = 32; off > 0; off >>= 1) {
#pragma unroll
      for (int j = 0; j < 9; j++) sj[j] += __shfl_xor(sj[j], off);
    }
    float wv = sj[0];
#pragma unroll
    for (int j = 1; j < 9; j++)
      if (l == j) wv = sj[j];
    if (l < 9) E[(b * 2048 + k0 + ki) * 9 + l] = __expf(wv);
  }
}

// ---------------------------------------------------------------------------
// per-iter wide GEMM: fwP = ctx @ Wfuse (N=2050). KSg=32, NB=33 -> 1056 blocks
// ---------------------------------------------------------------------------
__global__ __launch_bounds__(256) void k_fw(const float* __restrict__ ctx,
                                            const float* __restrict__ wfuse,
                                            float* __restrict__ outp) {
  __shared__ float As[512];
  const int t = threadIdx.x;
  const int ks = blockIdx.x / 33, nb = blockIdx.x % 33;
  const int kb = ks * 32;
  for (int idx = t; idx < 512; idx += 256) {
    As[idx] = ctx[((idx >> 5) << 10) + kb + (idx & 31)];
  }
  __syncthreads();
  const int nl = t & 63, mg = t >> 6;
  const int n = nb * 64 + nl;
  const bool nok = (n < 2050);
  const float* Bc = wfuse + n;
  float acc[4] = {0.f, 0.f, 0.f, 0.f};
  for (int k4 = 0; k4 < 32; k4 += 4) {
    float bv[4];
#pragma unroll
    for (int u = 0; u < 4; u++) bv[u] = nok ? Bc[(kb + k4 + u) * 2056] : 0.f;
#pragma unroll
    for (int i = 0; i < 4; i++) {
      const float4 av = *(const float4*)&As[((mg + 4 * i) << 5) + k4];
      acc[i] = fmaf(av.x, bv[0], acc[i]);
      acc[i] = fmaf(av.y, bv[1], acc[i]);
      acc[i] = fmaf(av.z, bv[2], acc[i]);
      acc[i] = fmaf(av.w, bv[3], acc[i]);
    }
  }
  if (nok) {
#pragma unroll
    for (int i = 0; i < 4; i++) outp[(ks * 16 + mg + 4 * i) * 2056 + n] = acc[i];
  }
}

// ---------------------------------------------------------------------------
// combine FW psums (P=32): opv (0..63), qslb (64..127), scalars (128)
// ---------------------------------------------------------------------------
__global__ __launch_bounds__(256) void k_combw(const float* __restrict__ fwP,
                                               const float* __restrict__ sqkcP,
                                               float* __restrict__ opv,
                                               float* __restrict__ qslb,
                                               float* __restrict__ gpre,
                                               float* __restrict__ gc,
                                               float* __restrict__ stopA) {
  const int bx = blockIdx.x;
  const int t = threadIdx.x;
  if (bx < 64) {
    const int i = bx * 256 + t;
    const int b = i >> 10, h = i & 1023;
    float s = 0.f;
    for (int p = 0; p < 32; p++) s += fwP[(p * 16 + b) * 2056 + h];
    opv[i] = s;
  } else if (bx < 128) {
    const int i = (bx - 64) * 256 + t;   // < 16384
    const int b = i >> 10, h = i & 1023;
    float s = 0.f;
    for (int p = 0; p < 32; p++) s += fwP[(p * 16 + b) * 2056 + 1024 + h];
    qslb[i] = s;
  } else {
    if (t < 16) {
      float g = 0.f, sa = 0.f;
      for (int p = 0; p < 32; p++) {
        g += fwP[(p * 16 + t) * 2056 + 2048];
        sa += fwP[(p * 16 + t) * 2056 + 2049];
      }
      gpre[t] = g;
      stopA[t] = sa;
    } else if (t < 25) {
      const int j = t - 16;
      float g = 0.f;
      for (int sp = 0; sp < 4; sp++) g += sqkcP[(sp * 9 + j) * 1025 + 1024];
      gc[j] = g;
    }
  }
}

// ---------------------------------------------------------------------------
// codebook argmax partials: 512 blocks x 16 codes. packed-u64 max.
// ---------------------------------------------------------------------------
__global__ __launch_bounds__(256) void k_cb(const float* __restrict__ opv,
                                            const float* __restrict__ cbv,
                                            const float* __restrict__ cbsqv,
                                            unsigned long long* __restrict__ opmaxp) {
  __shared__ __align__(16) char smem[65536];
  const int bx2 = blockIdx.x;
  const int t = threadIdx.x;
  for (int idx = t; idx < 16384; idx += 256) {
    const int x = idx << 2;
    *(float*)(smem + (x ^ (((x >> 7) & 7) << 4))) = opv[idx];
  }
  __syncthreads();
  const int w = t >> 6, l = t & 63;
  const int bxl = 64 * l;
  const int key = ((bxl >> 7) & 7) << 4;
  const int o0 = bxl ^ key, o1 = (bxl + 16) ^ key, o2 = (bxl + 32) ^ key, o3 = (bxl + 48) ^ key;
  unsigned long long bk[16];
#pragma unroll
  for (int m = 0; m < 16; m++) bk[m] = 0ull;
  const int cbase = (bx2 << 4) + (w << 2);
  for (int ci = 0; ci < 4; ci++) {
    const int c = cbase + ci;
    const float4* cr = (const float4*)(cbv + (c << 10));
    const float4 c0 = cr[4 * l], c1 = cr[4 * l + 1], c2 = cr[4 * l + 2], c3 = cr[4 * l + 3];
    float sm[16];
#pragma unroll
    for (int m = 0; m < 16; m++) {
      const char* qp = smem + (m << 12);
      const float4 a0 = *(const float4*)(qp + o0);
      const float4 a1 = *(const float4*)(qp + o1);
      const float4 a2 = *(const float4*)(qp + o2);
      const float4 a3 = *(const float4*)(qp + o3);
      sm[m] = dot4(a0, c0) + dot4(a1, c1) + dot4(a2, c2) + dot4(a3, c3);
    }
#pragma unroll
    for (int off = 32; off > 0; off >>= 1) {
#pragma unroll
      for (int m = 0; m < 16; m++) sm[m] += __shfl_xor(sm[m], off);
    }
    const float cq = cbsqv[c];
#pragma unroll
    for (int m = 0; m < 16; m++) {
      const float sc = fmaf(2.f, sm[m], -cq);
      const unsigned long long k2 = ((unsigned long long)sortable(sc) << 32) | (unsigned)(8192 - c);
      bk[m] = k2 > bk[m] ? k2 : bk[m];
    }
  }
  __syncthreads();
  unsigned long long* red = (unsigned long long*)smem;
  if (l == 0) {
#pragma unroll
    for (int m = 0; m < 16; m++) red[w * 16 + m] = bk[m];
  }
  __syncthreads();
  if (t < 16) {
    unsigned long long b2 = red[t];
    for (int ww = 1; ww < 4; ww++) {
      const unsigned long long v = red[ww * 16 + t];
      b2 = v > b2 ? v : b2;
    }
    opmaxp[bx2 * 16 + t] = b2;
  }
}

// ---------------------------------------------------------------------------
// per-iter slot attention via E-decomposition: wexp = exp(qslb.p) * E.
// grid (32,16), 512 threads. phase1: wave w keys 8 (1 dot each); phase2: PV
// (wave w covers 128 cols float2). LDS ~3 KB -> high occupancy.
// ---------------------------------------------------------------------------
__global__ __launch_bounds__(512) void k_slot(const float* __restrict__ prompt,
                                              const float* __restrict__ qslb,
                                              const float* __restrict__ E,
                                              float* __restrict__ accp,
                                              float* __restrict__ lpsum) {
  __shared__ float wl[64 * 10];
  __shared__ float lred[8 * 9];
  const int b = blockIdx.y, kc = blockIdx.x;
  const int t = threadIdx.x;
  const int w = t >> 6, l = t & 63;
  const float4* qp = (const float4*)(qslb + (b << 10) + 16 * l);
  const float4 q0 = qp[0], q1 = qp[1], q2 = qp[2], q3 = qp[3];
  const int kbase = kc * 64 + w * 8;
  float lacc = 0.f;
  const float* pbase = prompt + ((b * 2048 + kbase) << 10) + 16 * l;
  for (int ki = 0; ki < 8; ki++) {
    const float4* pr = (const float4*)(pbase + (ki << 10));
    const float4 p0 = pr[0], p1 = pr[1], p2 = pr[2], p3 = pr[3];
    float s = dot4(q0, p0) + dot4(q1, p1) + dot4(q2, p2) + dot4(q3, p3);
#pragma unroll
    for (int off = 32; off > 0; off >>= 1) s += __shfl_xor(s, off);
    const float we = __expf(s);
    if (l < 9) {
      const float wv = we * E[(b * 2048 + kbase + ki) * 9 + l];
      wl[(w * 8 + ki) * 10 + l] = wv;
      lacc += wv;
    }
  }
  if (l < 9) lred[w * 9 + l] = lacc;
  __syncthreads();
  if (t < 9) {
    float s = 0.f;
#pragma unroll
    for (int ww = 0; ww < 8; ww++) s += lred[ww * 9 + t];
    lpsum[(b * 32 + kc) * 9 + t] = s;
  }
  // phase 2: PV
  const int h2 = (w << 7) + (l << 1);
  float2 acc[9];
#pragma unroll
  for (int j = 0; j < 9; j++) acc[j] = make_float2(0.f, 0.f);
  const float* pb2 = prompt + ((b * 2048 + kc * 64) << 10) + h2;
#pragma unroll 4
  for (int k = 0; k < 64; k++) {
    const float2 pv = *(const float2*)(pb2 + (k << 10));
    const float* wr = &wl[k * 10];
#pragma unroll
    for (int j = 0; j < 9; j++) {
      acc[j].x = fmaf(wr[j], pv.x, acc[j].x);
      acc[j].y = fmaf(wr[j], pv.y, acc[j].y);
    }
  }
  float* ob = accp + (((kc * 16 + b) * 9) << 10) + h2;
#pragma unroll
  for (int j = 0; j < 9; j++) *(float2*)(ob + (j << 10)) = acc[j];
}

// ---------------------------------------------------------------------------
// flash attention, state pass: 256 chunks of 8 keys, grid (64,16).
// inline 8-psum q combine.
// ---------------------------------------------------------------------------
__global__ __launch_bounds__(256) void k_flash_state(const float* __restrict__ prompt,
                                                     const float* __restrict__ qs1P,
                                                     float* __restrict__ accst,
                                                     float* __restrict__ lst) {
  const int b = blockIdx.y;
  const int w = threadIdx.x >> 6, l = threadIdx.x & 63;
  const int chunk = blockIdx.x * 4 + w;  // 0..255
  float4 q0 = make_float4(0.f, 0.f, 0.f, 0.f), q1 = q0, q2 = q0, q3 = q0;
#pragma unroll
  for (int s = 0; s < 8; s++) {
    const float4* qp = (const float4*)(qs1P + ((s * 16 + b) << 10) + 16 * l);
    ADD4(q0, qp[0]); ADD4(q1, qp[1]); ADD4(q2, qp[2]); ADD4(q3, qp[3]);
  }
  float4 acc[4];
#pragma unroll
  for (int r = 0; r < 4; r++) acc[r] = make_float4(0.f, 0.f, 0.f, 0.f);
  float lsum = 0.f;
  const float* pbase = prompt + ((b * 2048 + chunk * 8) << 10) + 16 * l;
#pragma unroll 2
  for (int k = 0; k < 8; k++) {
    const float4* pr = (const float4*)(pbase + (k << 10));
    const float4 p0 = pr[0], p1 = pr[1], p2 = pr[2], p3 = pr[3];
    float s = dot4(q0, p0) + dot4(q1, p1) + dot4(q2, p2) + dot4(q3, p3);
#pragma unroll
    for (int off = 32; off > 0; off >>= 1) s += __shfl_xor(s, off);
    const float wgt = __expf(s);
    lsum += wgt;
    AXPY4(acc[0], wgt, p0); AXPY4(acc[1], wgt, p1);
    AXPY4(acc[2], wgt, p2); AXPY4(acc[3], wgt, p3);
  }
  float* ob = accst + ((chunk * 16 + b) << 10) + 16 * l;
#pragma unroll
  for (int r = 0; r < 4; r++) ((float4*)ob)[r] = acc[r];
  if (l == 0) lst[chunk * 16 + b] = lsum;
}

// combine state flash psums (256 chunks): ctx[b][h]. grid 256.
__global__ __launch_bounds__(256) void k_cst(const float* __restrict__ accst,
                                             const float* __restrict__ lst,
                                             float* __restrict__ ctx) {
  __shared__ float4 sred[256];
  __shared__ float rinv;
  const int bx = blockIdx.x;
  const int b = bx >> 4, hq = bx & 15;
  const int t = threadIdx.x;
  if (t < 64) {
    float s = 0.f;
    for (int c = t; c < 256; c += 64) s += lst[c * 16 + b];
#pragma unroll
    for (int off = 32; off > 0; off >>= 1) s += __shfl_xor(s, off);
    if (t == 0) rinv = 1.f / s;
  }
  const int h4 = hq * 16 + (t & 15);
  const int cp = t >> 4;
  float4 a = make_float4(0.f, 0.f, 0.f, 0.f);
#pragma unroll
  for (int ci = 0; ci < 16; ci++) {
    const int c = cp * 16 + ci;
    const float4 v = ((const float4*)accst)[((c * 16 + b) << 8) + h4];
    ADD4(a, v);
  }
  sred[t] = a;
  __syncthreads();
  if (t < 16) {
    float4 s = sred[t];
    for (int p2 = 1; p2 < 16; p2++) {
      const float4 v = sred[p2 * 16 + t];
      ADD4(s, v);
    }
    s.x *= rinv; s.y *= rinv; s.z *= rinv; s.w *= rinv;
    ((float4*)ctx)[(b << 8) + hq * 16 + t] = s;
  }
}

// ---------------------------------------------------------------------------
// K7: mask + masked mean (blocks 0..63); block 64: argmax finish (512 chunks)
// ---------------------------------------------------------------------------
__global__ __launch_bounds__(256) void k_k7(const float* __restrict__ accp,
                                            const float* __restrict__ lpsum,
                                            const float* __restrict__ gpre_g,
                                            const float* __restrict__ gc_g,
                                            const float* __restrict__ bgate,
                                            const unsigned long long* __restrict__ opmax,
                                            int* __restrict__ opidx,
                                            float* __restrict__ ssum) {
  __shared__ unsigned long long red[256];
  __shared__ float rl[9];
  __shared__ float gpre[16];
  __shared__ float gcs[9];
  __shared__ int mask_s[9];
  __shared__ float cntInv;
  const int bx = blockIdx.x;
  const int t = threadIdx.x;
  if (bx == 64) {
    const int b = t & 15, part = t >> 4;
    unsigned long long best = 0ull;
    for (int c = part * 32; c < part * 32 + 32; c++) {
      const unsigned long long v = opmax[c * 16 + b];
      best = v > best ? v : best;
    }
    red[t] = best;
    __syncthreads();
    if (t < 16) {
      unsigned long long m = red[t];
      for (int p2 = 1; p2 < 16; p2++) {
        const unsigned long long v = red[p2 * 16 + t];
        m = v > m ? v : m;
      }
      opidx[t] = 8192 - (int)(unsigned)(m & 0xFFFFFFFFull);
    }
    return;
  }
  const int b = bx >> 2;
  if (t < 9) {
    float s = 0.f;
    for (int c = 0; c < 32; c++) s += lpsum[(b * 32 + c) * 9 + t];
    rl[t] = 1.f / s;
  }
  if (t >= 32 && t < 48) gpre[t - 32] = gpre_g[t - 32];
  if (t >= 48 && t < 57) gcs[t - 48] = gc_g[t - 48];
  __syncthreads();
  if (t == 0) {
    const float bg = bgate[0];
    bool any = false;
    for (int bb = 0; bb < 16; bb++)
      for (int j = 0; j < 9; j++)
        if (gpre[bb] + gcs[j] + bg >= 0.f) any = true;
    int cnt = 0;
    if (any) {
      for (int j = 0; j < 9; j++) {
        const int s = (gpre[b] + gcs[j] + bg >= 0.f) ? 1 : 0;
        mask_s[j] = s;
        cnt += s;
      }
    } else {
      float bv = -3.4e38f;
      int bj = 0;
      for (int j = 0; j < 9; j++) {
        const float v = gpre[b] + gcs[j] + bg;
        if (v > bv) { bv = v; bj = j; }
      }
      for (int j = 0; j < 9; j++) mask_s[j] = (j == bj) ? 1 : 0;
      cnt = 1;
    }
    cntInv = 1.f / (float)(cnt > 0 ? cnt : 1);
  }
  __syncthreads();
  const int h = ((bx & 3) << 8) + t;
  float v = 0.f;
  for (int j = 0; j < 9; j++) {
    if (mask_s[j]) {
      float s = 0.f;
      for (int c = 0; c < 32; c++) s += accp[(((c * 16 + b) * 9 + j) << 10) + h];
      v = fmaf(s, rl[j], v);
    }
  }
  ssum[(b << 10) + h] = v * cntInv;
}

// ---------------------------------------------------------------------------
// GRU GEMM with fused ms = tanh(op_emb + sum k8p) A-stage.
// blocks 0..383 = ms@Wih (nb==0 writes ms + d_out), 384..767 = state@Whh.
// ---------------------------------------------------------------------------
__global__ __launch_bounds__(256) void k_gru(const float* __restrict__ k8p,
                                             const int* __restrict__ opidx,
                                             const float* __restrict__ cbv,
                                             const float* __restrict__ state,
                                             const float* __restrict__ Wih,
                                             const float* __restrict__ Whh,
                                             float* __restrict__ gpP,
                                             float* __restrict__ ms,
                                             float* __restrict__ dout, int it) {
  __shared__ float As[2048];
  const int bx = blockIdx.x;
  const int t = threadIdx.x;
  const int half = (bx >= 384) ? 1 : 0;
  const int b2 = half ? bx - 384 : bx;
  const int ks = b2 / 48, nb = b2 % 48;
  const int kb = ks * 128;
  for (int idx = t; idx < 2048; idx += 256) {
    const int m = idx >> 7, kl = idx & 127;
    float v;
    if (!half) {
      float s = 0.f;
      for (int p = 0; p < 16; p++) s += k8p[((p * 16 + m) << 10) + kb + kl];
      v = tanhf(s + cbv[(opidx[m] << 10) + kb + kl]);
      if (nb == 0) {
        ms[(m << 10) + kb + kl] = v;
        dout[(m << 12) + (it << 10) + kb + kl] = v;
      }
    } else {
      v = state[(m << 10) + kb + kl];
    }
    As[idx] = v;
  }
  __syncthreads();
  const int nl = t & 63, mg = t >> 6;
  const int n = nb * 64 + nl;
  const float* Bc = (half ? Whh : Wih) + n;
  float acc[4] = {0.f, 0.f, 0.f, 0.f};
  for (int k4 = 0; k4 < 128; k4 += 4) {
    float bv[4];
#pragma unroll
    for (int u = 0; u < 4; u++) bv[u] = Bc[(kb + k4 + u) * 3072];
#pragma unroll
    for (int i = 0; i < 4; i++) {
      const float4 av = *(const float4*)&As[((mg + 4 * i) << 7) + k4];
      acc[i] = fmaf(av.x, bv[0], acc[i]);
      acc[i] = fmaf(av.y, bv[1], acc[i]);
      acc[i] = fmaf(av.z, bv[2], acc[i]);
      acc[i] = fmaf(av.w, bv[3], acc[i]);
    }
  }
  float* outp = gpP + half * 3072;
#pragma unroll
  for (int i = 0; i < 4; i++) outp[(ks * 16 + mg + 4 * i) * 6144 + n] = acc[i];
}

// ---------------------------------------------------------------------------
// K9b: GRU elementwise finish (0..63) + stop logits (64..67)
// ---------------------------------------------------------------------------
__global__ __launch_bounds__(256) void k_k9b(const float* __restrict__ gp,
                                             const float* __restrict__ bih,
                                             const float* __restrict__ bhh,
                                             float* __restrict__ state,
                                             const float* __restrict__ stopA,
                                             const float* __restrict__ ms,
                                             const float* __restrict__ Wstop,
                                             const float* __restrict__ bstop,
                                             float* __restrict__ dout, int it) {
  const int bx = blockIdx.x;
  const int t = threadIdx.x;
  if (bx < 64) {
    const int gi = bx * 256 + t;
    const int b = gi >> 10, h = gi & 1023;
    float ir = 0.f, iz = 0.f, inn = 0.f, hr = 0.f, hz = 0.f, hn = 0.f;
    for (int s = 0; s < 8; s++) {
      const float* g = gp + (s * 16 + b) * 6144;
      ir += g[h]; iz += g[1024 + h]; inn += g[2048 + h];
      hr += g[3072 + h]; hz += g[4096 + h]; hn += g[5120 + h];
    }
    ir += bih[h]; iz += bih[1024 + h]; inn += bih[2048 + h];
    hr += bhh[h]; hz += bhh[1024 + h]; hn += bhh[2048 + h];
    const float r = 1.f / (1.f + __expf(-(ir + hr)));
    const float z = 1.f / (1.f + __expf(-(iz + hz)));
    const float n = tanhf(fmaf(r, hn, inn));
    const float hold = state[gi];
    state[gi] = (1.f - z) * n + z * hold;
  } else {
    const int wid = (bx - 64) * 4 + (t >> 6);
    const int l = t & 63;
    float p = 0.f;
    for (int i = 0; i < 16; i++) {
      const int h = l + (i << 6);
      p = fmaf(ms[(wid << 10) + h], Wstop[1024 + h], p);
    }
#pragma unroll
    for (int off = 32; off > 0; off >>= 1) p += __shfl_xor(p, off);
    if (l == 0) {
      const float lg = p + stopA[wid] + bstop[0];
      dout[65536 + wid * 4 + it] = lg;
      dout[65600 + wid * 4 + it] = 1.f / (1.f + __expf(-lg));
    }
  }
}

__global__ void k_k10(float* __restrict__ dout) {
  const int t = threadIdx.x;
  if (t < 16) {
    int cl = 4;
    for (int it = 0; it < 4; it++) {
      if (dout[65536 + t * 4 + it] >= 0.f) { cl = it + 1; break; }
    }
    dout[65664 + t] = (float)cl;
  }
}

// --------------------------- setup kernels ---------------------------------
__global__ __launch_bounds__(256) void k_meanpsum(const float* __restrict__ src,
                                                  float* __restrict__ out, int rpc) {
  const int s = blockIdx.x, b = blockIdx.y, t = threadIdx.x;
  const int R = gridDim.x * rpc;
  const float4* base = (const float4*)src + (size_t)(b * R + s * rpc) * 256 + t;
  float4 acc = make_float4(0.f, 0.f, 0.f, 0.f);
#pragma unroll 4
  for (int r = 0; r < rpc; r++) {
    const float4 v = base[r * 256];
    ADD4(acc, v);
  }
  ((float4*)out)[((s * 16 + b) << 8) + t] = acc;
}

__global__ __launch_bounds__(256) void k_cbsq(const float* __restrict__ cbv,
                                              float* __restrict__ out) {
  const int c = blockIdx.x * 4 + (threadIdx.x >> 6);
  const int l = threadIdx.x & 63;
  const float4* cr = (const float4*)(cbv + (c << 10));
  float s = 0.f;
#pragma unroll
  for (int r = 0; r < 4; r++) {
    const float4 v = cr[4 * l + r];
    s += dot4(v, v);
  }
#pragma unroll
  for (int off = 32; off > 0; off >>= 1) s += __shfl_xor(s, off);
  if (l == 0) out[c] = s;
}

__global__ __launch_bounds__(256) void k_meancat(const float* __restrict__ pmp,
                                                 const float* __restrict__ lmp,
                                                 float* __restrict__ mean) {
  const int gi = blockIdx.x * 256 + threadIdx.x;
  const int b = gi >> 11, k = gi & 2047;
  float v = 0.f;
  if (k < 1024) {
    for (int s = 0; s < 64; s++) v += pmp[((s * 16 + b) << 10) + k];
    v *= (1.f / 2048.f);
  } else {
    const int kk = k - 1024;
    for (int s = 0; s < 16; s++) v += lmp[((s * 16 + b) << 10) + kk];
    v *= (1.f / 512.f);
  }
  mean[b * 2048 + k] = v;
}

__global__ __launch_bounds__(256) void k_s2b(const float* __restrict__ s2p,
                                             float* __restrict__ state) {
  const int gi = blockIdx.x * 256 + threadIdx.x;
  const int b = gi >> 10, h = gi & 1023;
  float s = 0.f;
  for (int si = 0; si < 8; si++) s += s2p[((si * 16 + b) << 10) + h];
  state[gi] = tanhf(s);
}

// ---------------------------------------------------------------------------
// workspace layout (floats), ~13.0M floats = 52 MB (ws is ~512 MB)
// ---------------------------------------------------------------------------
// persistent
static constexpr int F_CBSQ  = 0;                    // 8192
static constexpr int F_STATE = 8192;                 // 16384
static constexpr int F_WQK   = 24576;                // 1048576
static constexpr int F_T1    = F_WQK + 1048576;      // 1048576
static constexpr int F_WFUSE = F_T1 + 1048576;       // 2105344
static constexpr int F_SQKCP = F_WFUSE + 2105344;    // 36928
static constexpr int F_E     = F_SQKCP + 36928;      // 294912
static constexpr int F_UN    = F_E + 294912;         // union region, 8421376
// setup phase A (dead before wgemmT)
static constexpr int F_PMP   = F_UN;                 // 1048576
static constexpr int F_LMP   = F_PMP + 1048576;      // 262144
static constexpr int F_MEAN  = F_LMP + 262144;       // 32768
static constexpr int F_S2P   = F_MEAN + 32768;       // 131072
// setup phase B (psums)
static constexpr int F_WQKP  = F_UN;                 // 4194304
static constexpr int F_T1P   = F_UN + 4194304;       // 4194304
// setup phase C
static constexpr int F_WFP   = F_UN;                 // 8421376
// per-iter
static constexpr int F_QS1   = F_UN;                 // 8*16384 = 131072
static constexpr int F_LST   = F_QS1 + 131072;       // 4096
static constexpr int F_CTX   = F_LST + 4096;         // 16384
static constexpr int F_FWP   = F_CTX + 16384;        // 32*16*2056 = 1052672
static constexpr int F_OPV   = F_FWP + 1052672;      // 16384
static constexpr int F_OPMAX = F_OPV + 16384;        // u64[8192] = 16384 floats
static constexpr int F_OPIDX = F_OPMAX + 16384;      // 64
static constexpr int F_GPRE  = F_OPIDX + 64;         // 64
static constexpr int F_GC    = F_GPRE + 64;          // 64
static constexpr int F_STOPA = F_GC + 64;            // 64
static constexpr int F_QSLB  = F_STOPA + 64;         // 16384
static constexpr int F_LPS   = F_QSLB + 16384;       // 4672
static constexpr int F_SSUM  = F_LPS + 4672;         // 16384
static constexpr int F_MS    = F_SSUM + 16384;       // 16384
static constexpr int F_GP    = F_MS + 16384;         // 786432
static constexpr int F_K8P   = F_GP + 786432;        // 262144
static constexpr int F_BIG   = F_K8P + 262144;       // max(accst 4.19M, accp 4.72M)
static constexpr int F_END   = F_UN + 8421376;

static SG baseSG() {
  SG p;
  p.Bm = nullptr; p.Bg = nullptr; p.a0 = nullptr; p.out = nullptr;
  p.M = 16; p.N = 1024; p.Ncore = 1024;
  p.NB = 16; p.kslice = 64; p.ksh = 6;
  p.lda = 1024; p.ldb = 1024; p.ldo = 1024;
  p.mr = 4; p.scale = 1.f;
  return p;
}

extern "C" void kernel_launch(void* const* d_in, const int* in_sizes, int n_in,
                              void* d_out, int out_size, void* d_ws, size_t ws_size,
                              hipStream_t stream) {
  (void)in_sizes; (void)n_in; (void)out_size; (void)ws_size;
  const float* logic  = (const float*)d_in[0];
  const float* prompt = (const float*)d_in[1];
  const float* cbv    = (const float*)d_in[2];
  const float* W_init = (const float*)d_in[3];
  const float* W_pq   = (const float*)d_in[4];
  const float* W_pk   = (const float*)d_in[5];
  const float* W_pv   = (const float*)d_in[6];
  const float* slotq  = (const float*)d_in[7];
  const float* W_sq   = (const float*)d_in[8];
  const float* W_op   = (const float*)d_in[9];
  const float* W_gate = (const float*)d_in[10];
  const float* b_gate = (const float*)d_in[11];
  const float* W_stop = (const float*)d_in[12];
  const float* b_stop = (const float*)d_in[13];
  const float* Wih    = (const float*)d_in[14];
  const float* Whh    = (const float*)d_in[15];
  const float* bih    = (const float*)d_in[16];
  const float* bhh    = (const float*)d_in[17];
  float* out = (float*)d_out;
  float* w = (float*)d_ws;

  const float inv32 = 1.0f / 32.0f;

  // ---- setup phase A: means + state init ----
  k_meanpsum<<<dim3(64, 16), 256, 0, stream>>>(prompt, w + F_PMP, 32);
  k_meanpsum<<<dim3(16, 16), 256, 0, stream>>>(logic, w + F_LMP, 32);
  k_cbsq<<<2048, 256, 0, stream>>>(cbv, w + F_CBSQ);
  k_meancat<<<128, 256, 0, stream>>>(w + F_PMP, w + F_LMP, w + F_MEAN);
  {
    SG p = baseSG();
    p.a0 = w + F_MEAN; p.Bm = W_init; p.out = w + F_S2P;
    p.kslice = 256; p.ksh = 8; p.lda = 2048; p.NB = 16;  // KSg=8 -> 128 blocks
    k_sgemm<<<128, 256, 0, stream>>>(p);
  }
  k_s2b<<<64, 256, 0, stream>>>(w + F_S2P, w + F_STATE);
  // ---- setup phase B: Wqk, T1 (split-K) ----
  k_wgemmT<<<2048, 256, 0, stream>>>(W_pq, W_pk, w + F_WQKP, W_sq, w + F_T1P);
  k_combT<<<8192, 256, 0, stream>>>(w + F_WQKP, w + F_T1P, w + F_WQK, w + F_T1, inv32);
  // sqkcP = slotq @ [T1 | W_gate]  (4 psums, M=9, N=1025)
  {
    SG p = baseSG();
    p.a0 = slotq; p.Bm = w + F_T1; p.Bg = W_gate;
    p.M = 9; p.N = 1025; p.Ncore = 1024; p.NB = 17;
    p.kslice = 256; p.ksh = 8; p.out = w + F_SQKCP; p.ldo = 1025; p.mr = 7;
    k_sgemm<<<68, 256, 0, stream>>>(p);
  }
  // E[b][k][9] = exp(sqk_j . p_bk)  (iteration-invariant)
  k_E<<<dim3(32, 16), 512, 0, stream>>>(prompt, w + F_SQKCP, w + F_E);
  // ---- setup phase C: Wfuse (split-K) ----
  k_wgemmF<<<2112, 256, 0, stream>>>(W_pv, W_op, w + F_T1, W_gate, W_stop, w + F_WFP);
  k_combF<<<8224, 256, 0, stream>>>(w + F_WFP, w + F_WFUSE);

  for (int it = 0; it < 4; ++it) {
    // qs1P = state @ Wqk (8 psums)
    {
      SG p = baseSG();
      p.a0 = w + F_STATE; p.Bm = w + F_WQK; p.out = w + F_QS1;
      p.kslice = 128; p.ksh = 7; p.NB = 16;
      k_sgemm<<<128, 256, 0, stream>>>(p);
    }
    // flash state attention (256 chunks of 8 keys)
    k_flash_state<<<dim3(64, 16), 256, 0, stream>>>(prompt, w + F_QS1, w + F_BIG, w + F_LST);
    k_cst<<<256, 256, 0, stream>>>(w + F_BIG, w + F_LST, w + F_CTX);
    // fw = ctx @ Wfuse  (32 psums, N=2050)
    k_fw<<<1056, 256, 0, stream>>>(w + F_CTX, w + F_WFUSE, w + F_FWP);
    // combine: opv, qslb, gate/stop scalars
    k_combw<<<129, 256, 0, stream>>>(w + F_FWP, w + F_SQKCP, w + F_OPV, w + F_QSLB,
                                     w + F_GPRE, w + F_GC, w + F_STOPA);
    // codebook argmax partials
    k_cb<<<512, 256, 0, stream>>>(w + F_OPV, cbv, w + F_CBSQ,
                                  (unsigned long long*)(w + F_OPMAX));
    // slot attention (E-decomposed)
    k_slot<<<dim3(32, 16), 512, 0, stream>>>(prompt, w + F_QSLB, w + F_E,
                                             w + F_BIG, w + F_LPS);
    // K7: mask + masked mean (+ argmax finish)
    k_k7<<<65, 256, 0, stream>>>(w + F_BIG, w + F_LPS, w + F_GPRE, w + F_GC, b_gate,
                                 (const unsigned long long*)(w + F_OPMAX),
                                 (int*)(w + F_OPIDX), w + F_SSUM);
    // k8pP = ssum @ W_pv (16 psums)
    {
      SG p = baseSG();
      p.a0 = w + F_SSUM; p.Bm = W_pv; p.out = w + F_K8P;
      k_sgemm<<<256, 256, 0, stream>>>(p);
    }
    // GRU GEMM with fused ms A-stage (writes ms + d_out summary)
    k_gru<<<768, 256, 0, stream>>>(w + F_K8P, (const int*)(w + F_OPIDX), cbv,
                                   w + F_STATE, Wih, Whh, w + F_GP, w + F_MS, out, it);
    // GRU finish + stop logits/probs
    k_k9b<<<68, 256, 0, stream>>>(w + F_GP, bih, bhh, w + F_STATE, w + F_STOPA,
                                  w + F_MS, W_stop, b_stop, out, it);
  }
  k_k10<<<1, 64, 0, stream>>>(out);
}